// Round 15
// baseline (579.865 us; speedup 1.0000x reference)
//
#include <hip/hip_runtime.h>
#include <math.h>

#define N_NODES 50000
#define N_EDGES 800000
#define E_TOT   850000
#define N_GRAPHS 64
#define EMB 128
#define HID 64
#define HEADS 4
#define NEG_SLOPE 0.2f
#define EPS 1e-16f
#define MAX_DEG 64
#define ELL_NB 64
#define ELL_NODES ((N_NODES + ELL_NB - 1) / ELL_NB)   // 782 nodes per block

typedef short bf16x8 __attribute__((ext_vector_type(8)));
typedef float f32x4  __attribute__((ext_vector_type(4)));

__device__ __forceinline__ float leaky(float x) { return x >= 0.f ? x : NEG_SLOPE * x; }
__device__ __forceinline__ float elu(float x)   { return x > 0.f ? x : expf(x) - 1.f; }

__device__ __forceinline__ unsigned short f2bf(float f) {
    unsigned u = __float_as_uint(f);
    return (unsigned short)((u + 0x7FFFu + ((u >> 16) & 1u)) >> 16);
}
__device__ __forceinline__ float bf2f(unsigned short h) {
    return __uint_as_float((unsigned)h << 16);
}

__device__ __forceinline__ int lbound(const int* __restrict__ a, int n, int v) {
    int lo = 0, hi = n;
    while (lo < hi) { int mid = (lo + hi) >> 1; if (a[mid] < v) lo = mid + 1; else hi = mid; }
    return lo;
}

// ---- ELL build via block-partitioned scan: NO global atomics ----
// block b owns nodes [b*782, ...); streams dst[] (3.2 MB, L2-resident), claims
// matching edges via LDS atomics; ell rows are block-exclusive (no line bouncing).
// Self-loop goes in slot 0 (free init); cnt written once at the end.
__global__ __launch_bounds__(1024)
void k_ell2(const int* __restrict__ ei, unsigned* __restrict__ cnt,
            unsigned short* __restrict__ ell) {
    __shared__ unsigned lcnt[ELL_NODES];
    int base = blockIdx.x * ELL_NODES;
    int nOwn = min(base + ELL_NODES, N_NODES) - base;
    for (int i = threadIdx.x; i < nOwn; i += 1024) {
        lcnt[i] = 1;
        ell[(size_t)(base + i) * MAX_DEG] = (unsigned short)(base + i);
    }
    __syncthreads();
    const int* dsts = ei + N_EDGES;
    for (int e = threadIdx.x; e < N_EDGES; e += 1024) {
        int d = dsts[e];
        unsigned rel = (unsigned)(d - base);
        if (rel < (unsigned)nOwn) {
            unsigned slot = atomicAdd(&lcnt[rel], 1u);
            if (slot < MAX_DEG)
                ell[(size_t)d * MAX_DEG + slot] = (unsigned short)ei[e];
        }
    }
    __syncthreads();
    for (int i = threadIdx.x; i < nOwn; i += 1024)
        cnt[base + i] = lcnt[i];
}

// ---- weight prep (parallel) ----
__global__ void k_wprep(const float* __restrict__ W1, const float* __restrict__ as1, const float* __restrict__ ad1,
                        const float* __restrict__ W2, const float* __restrict__ as2, const float* __restrict__ ad2,
                        const float* __restrict__ Wg1,
                        unsigned short* __restrict__ W1t, float* __restrict__ v1s, float* __restrict__ v1d,
                        unsigned short* __restrict__ W2t, float* __restrict__ v2s, float* __restrict__ v2d,
                        unsigned short* __restrict__ wg1h, unsigned short* __restrict__ wg1l) {
    int b = blockIdx.x, t = threadIdx.x;
    if (b < 32) {
        for (int i = b * 1024 + t; i < (b + 1) * 1024; i += 256) {
            int c = i >> 7, k = i & 127;
            W1t[i] = f2bf(W1[k * 256 + c]);
        }
    } else if (b < 48) {
        int bb = b - 32;
        for (int i = bb * 1024 + t; i < (bb + 1) * 1024; i += 256) {
            int c = i >> 8, k = i & 255;
            W2t[i] = f2bf(W2[k * 64 + c]);
        }
    } else if (b == 48) {
        for (int i = t; i < 512; i += 256) {
            int h = i >> 7, k = i & 127;
            float s = 0.f, d = 0.f;
            for (int c = 0; c < 64; ++c) {
                float wv = W1[k * 256 + h * 64 + c];
                s = fmaf(wv, as1[h * 64 + c], s);
                d = fmaf(wv, ad1[h * 64 + c], d);
            }
            v1s[i] = s; v1d[i] = d;
        }
    } else if (b == 49) {
        float s = 0.f, d = 0.f;
        for (int cc = 0; cc < 64; ++cc) {
            float wv = W2[t * 64 + cc];
            s = fmaf(wv, as2[cc], s);
            d = fmaf(wv, ad2[cc], d);
        }
        v2s[t] = s; v2d[t] = d;
    } else {
        for (int i = t; i < 4096; i += 256) {
            int c = i >> 6, k = i & 63;
            float v = Wg1[k * 64 + c];
            unsigned short h = f2bf(v);
            wg1h[i] = h;
            wg1l[i] = f2bf(v - bf2f(h));
        }
    }
}

// ---- layer 1 GEMM via MFMA + fused attention logit dots (wave w = head w) ----
__global__ __launch_bounds__(256)
void k_gemm1_mfma(const float* __restrict__ x, const unsigned short* __restrict__ W1t,
                  const float* __restrict__ v1s, const float* __restrict__ v1d,
                  unsigned short* __restrict__ h1b, float* __restrict__ a_src1,
                  float* __restrict__ a_dst1) {
    int w = threadIdx.x >> 6, l = threadIdx.x & 63;
    int r = l & 15, kg = l >> 4;
    int tile = blockIdx.x;
    const float* xr = x + (size_t)(tile * 16 + r) * 128 + kg * 8;
    bf16x8 af[4];
    float ps = 0.f, pd = 0.f;
    #pragma unroll
    for (int j = 0; j < 4; ++j) {
        float4 f0 = *(const float4*)(xr + j * 32);
        float4 f1 = *(const float4*)(xr + j * 32 + 4);
        const float* vs = v1s + w * 128 + j * 32 + kg * 8;
        const float* vd = v1d + w * 128 + j * 32 + kg * 8;
        float4 s0 = *(const float4*)vs, s1 = *(const float4*)(vs + 4);
        float4 d0 = *(const float4*)vd, d1 = *(const float4*)(vd + 4);
        ps += f0.x*s0.x + f0.y*s0.y + f0.z*s0.z + f0.w*s0.w
            + f1.x*s1.x + f1.y*s1.y + f1.z*s1.z + f1.w*s1.w;
        pd += f0.x*d0.x + f0.y*d0.y + f0.z*d0.z + f0.w*d0.w
            + f1.x*d1.x + f1.y*d1.y + f1.z*d1.z + f1.w*d1.w;
        bf16x8 t;
        t[0] = (short)f2bf(f0.x); t[1] = (short)f2bf(f0.y);
        t[2] = (short)f2bf(f0.z); t[3] = (short)f2bf(f0.w);
        t[4] = (short)f2bf(f1.x); t[5] = (short)f2bf(f1.y);
        t[6] = (short)f2bf(f1.z); t[7] = (short)f2bf(f1.w);
        af[j] = t;
    }
    ps += __shfl_xor(ps, 16); ps += __shfl_xor(ps, 32);
    pd += __shfl_xor(pd, 16); pd += __shfl_xor(pd, 32);
    if (l < 16) {
        a_src1[(size_t)(tile * 16 + r) * 4 + w] = ps;
        a_dst1[(size_t)(tile * 16 + r) * 4 + w] = pd;
    }
    for (int cc = 0; cc < 4; ++cc) {
        int c0 = cc * 64 + w * 16;
        const bf16x8* B = (const bf16x8*)(W1t + (size_t)(c0 + r) * 128 + kg * 8);
        f32x4 acc = {0.f, 0.f, 0.f, 0.f};
        acc = __builtin_amdgcn_mfma_f32_16x16x32_bf16(af[0], B[0],  acc, 0, 0, 0);
        acc = __builtin_amdgcn_mfma_f32_16x16x32_bf16(af[1], B[4],  acc, 0, 0, 0);
        acc = __builtin_amdgcn_mfma_f32_16x16x32_bf16(af[2], B[8],  acc, 0, 0, 0);
        acc = __builtin_amdgcn_mfma_f32_16x16x32_bf16(af[3], B[12], acc, 0, 0, 0);
        #pragma unroll
        for (int j = 0; j < 4; ++j)
            h1b[(size_t)(tile * 16 + kg * 4 + j) * 256 + c0 + r] = f2bf(acc[j]);
    }
}

// ---- FUSED layer 1: node gather (pipelined) + softmax + ELU, then gemm2 MFMA in-block ----
__global__ __launch_bounds__(1024)
void k_layer1(const unsigned short* __restrict__ ell, const unsigned* __restrict__ cnt,
              const float4* __restrict__ asrc, const float4* __restrict__ adst,
              const unsigned short* __restrict__ h1b, const float4* __restrict__ bias,
              const float4* __restrict__ v2s4, const float4* __restrict__ v2d4,
              const unsigned short* __restrict__ W2t,
              float* __restrict__ a_src2, float* __restrict__ a_dst2,
              unsigned short* __restrict__ h2b) {
    __shared__ float sw[4][16][65];
    __shared__ int   ss[16][MAX_DEG];
    __shared__ unsigned short Ash[16][264];
    int wave = threadIdx.x >> 6, lane = threadIdx.x & 63;
    int node = blockIdx.x * 16 + wave;
    int deg = min((int)cnt[node], MAX_DEG);

    float4 ad = adst[node];
    float a0 = -INFINITY, a1 = -INFINITY, a2 = -INFINITY, a3 = -INFINITY;
    int s = 0;
    if (lane < deg) {
        s = ell[node * MAX_DEG + lane];
        float4 as = asrc[s];
        a0 = leaky(as.x + ad.x); a1 = leaky(as.y + ad.y);
        a2 = leaky(as.z + ad.z); a3 = leaky(as.w + ad.w);
    }
    float m0 = a0, m1 = a1, m2 = a2, m3 = a3;
    for (int o = 32; o > 0; o >>= 1) {
        m0 = fmaxf(m0, __shfl_xor(m0, o)); m1 = fmaxf(m1, __shfl_xor(m1, o));
        m2 = fmaxf(m2, __shfl_xor(m2, o)); m3 = fmaxf(m3, __shfl_xor(m3, o));
    }
    float w0 = lane < deg ? expf(a0 - m0) : 0.f;
    float w1 = lane < deg ? expf(a1 - m1) : 0.f;
    float w2 = lane < deg ? expf(a2 - m2) : 0.f;
    float w3 = lane < deg ? expf(a3 - m3) : 0.f;
    float t0 = w0, t1 = w1, t2 = w2, t3 = w3;
    for (int o = 32; o > 0; o >>= 1) {
        t0 += __shfl_xor(t0, o); t1 += __shfl_xor(t1, o);
        t2 += __shfl_xor(t2, o); t3 += __shfl_xor(t3, o);
    }
    w0 /= (t0 + EPS); w1 /= (t1 + EPS); w2 /= (t2 + EPS); w3 /= (t3 + EPS);
    if (lane < deg) {
        sw[0][wave][lane] = w0; sw[1][wave][lane] = w1;
        sw[2][wave][lane] = w2; sw[3][wave][lane] = w3;
        ss[wave][lane] = s;
    }
    int head = lane >> 4;
    float c0 = 0.f, c1 = 0.f, c2 = 0.f, c3 = 0.f;
    ushort4 hcur = *(const ushort4*)(h1b + (size_t)ss[wave][0] * 256 + lane * 4);
    float   wcur = sw[head][wave][0];
    for (int e = 1; e < deg; ++e) {
        ushort4 hnx = *(const ushort4*)(h1b + (size_t)ss[wave][e] * 256 + lane * 4);
        float   wnx = sw[head][wave][e];
        c0 = fmaf(bf2f(hcur.x), wcur, c0); c1 = fmaf(bf2f(hcur.y), wcur, c1);
        c2 = fmaf(bf2f(hcur.z), wcur, c2); c3 = fmaf(bf2f(hcur.w), wcur, c3);
        hcur = hnx; wcur = wnx;
    }
    c0 = fmaf(bf2f(hcur.x), wcur, c0); c1 = fmaf(bf2f(hcur.y), wcur, c1);
    c2 = fmaf(bf2f(hcur.z), wcur, c2); c3 = fmaf(bf2f(hcur.w), wcur, c3);

    float4 b = bias[lane];
    float o0 = elu(c0 + b.x), o1 = elu(c1 + b.y), o2 = elu(c2 + b.z), o3 = elu(c3 + b.w);
    *(ushort4*)&Ash[wave][lane * 4] = make_ushort4(f2bf(o0), f2bf(o1), f2bf(o2), f2bf(o3));
    float4 vs = v2s4[lane], vd = v2d4[lane];
    float ps = o0 * vs.x + o1 * vs.y + o2 * vs.z + o3 * vs.w;
    float pd = o0 * vd.x + o1 * vd.y + o2 * vd.z + o3 * vd.w;
    for (int o = 32; o > 0; o >>= 1) { ps += __shfl_xor(ps, o); pd += __shfl_xor(pd, o); }
    if (lane == 0) { a_src2[node] = ps; a_dst2[node] = pd; }

    __syncthreads();
    if (wave < 4) {
        int r = lane & 15, kg = lane >> 4;
        f32x4 acc = {0.f, 0.f, 0.f, 0.f};
        #pragma unroll
        for (int kk = 0; kk < 8; ++kk) {
            bf16x8 afr = *(const bf16x8*)&Ash[r][kg * 8 + kk * 32];
            bf16x8 bfr = *(const bf16x8*)(W2t + (size_t)(wave * 16 + r) * 256 + kg * 8 + kk * 32);
            acc = __builtin_amdgcn_mfma_f32_16x16x32_bf16(afr, bfr, acc, 0, 0, 0);
        }
        #pragma unroll
        for (int j = 0; j < 4; ++j)
            h2b[(size_t)(blockIdx.x * 16 + kg * 4 + j) * 64 + wave * 16 + r] = f2bf(acc[j]);
    }
}

// ---- FUSED layer 2: node gather (pipelined) + gate MFMA in-block ----
__global__ __launch_bounds__(1024)
void k_layer2(const unsigned short* __restrict__ ell, const unsigned* __restrict__ cnt,
              const float* __restrict__ asrc, const float* __restrict__ adst,
              const unsigned short* __restrict__ h2b, const float* __restrict__ bias,
              const unsigned short* __restrict__ wg1h, const unsigned short* __restrict__ wg1l,
              const float* __restrict__ bg1, const float* __restrict__ Wg2,
              const float* __restrict__ bg2,
              float* __restrict__ out2, float* __restrict__ gate) {
    __shared__ float sw[16][MAX_DEG];
    __shared__ int   ss[16][MAX_DEG];
    __shared__ unsigned short Ah[16][72], Al[16][72];
    __shared__ float gp[4][16];
    int wave = threadIdx.x >> 6, lane = threadIdx.x & 63;
    int half = lane >> 5, li = lane & 31;
    int node = blockIdx.x * 16 + wave;
    int deg = min((int)cnt[node], MAX_DEG);

    float adv = adst[node];
    float a = -INFINITY;
    int s = 0;
    if (lane < deg) {
        s = ell[node * MAX_DEG + lane];
        a = leaky(asrc[s] + adv);
    }
    float m = a;
    for (int o = 32; o > 0; o >>= 1) m = fmaxf(m, __shfl_xor(m, o));
    float w = lane < deg ? expf(a - m) : 0.f;
    float t = w;
    for (int o = 32; o > 0; o >>= 1) t += __shfl_xor(t, o);
    w /= (t + EPS);
    if (lane < deg) { sw[wave][lane] = w; ss[wave][lane] = s; }

    float c0 = 0.f, c1 = 0.f;
    int row = half;
    unsigned ucur = 0; float wcur = 0.f;
    if (row < deg) {
        ucur = *(const unsigned*)(h2b + (size_t)ss[wave][row] * 64 + li * 2);
        wcur = sw[wave][row];
    }
    while (row < deg) {
        int nrow = row + 2;
        unsigned unx = 0; float wnx = 0.f;
        if (nrow < deg) {
            unx = *(const unsigned*)(h2b + (size_t)ss[wave][nrow] * 64 + li * 2);
            wnx = sw[wave][nrow];
        }
        c0 = fmaf(__uint_as_float(ucur << 16), wcur, c0);
        c1 = fmaf(__uint_as_float(ucur & 0xffff0000u), wcur, c1);
        ucur = unx; wcur = wnx; row = nrow;
    }
    c0 += __shfl_xor(c0, 32);
    c1 += __shfl_xor(c1, 32);
    if (half == 0) {
        float o0 = elu(c0 + bias[li * 2]);
        float o1 = elu(c1 + bias[li * 2 + 1]);
        *(float2*)(out2 + (size_t)node * 64 + li * 2) = make_float2(o0, o1);
        unsigned short h0 = f2bf(o0), h1 = f2bf(o1);
        *(unsigned*)&Ah[wave][li * 2] = ((unsigned)h1 << 16) | h0;
        unsigned short l0 = f2bf(o0 - bf2f(h0)), l1 = f2bf(o1 - bf2f(h1));
        *(unsigned*)&Al[wave][li * 2] = ((unsigned)l1 << 16) | l0;
    }

    __syncthreads();
    if (wave < 4) {
        int r = lane & 15, kg = lane >> 4;
        const bf16x8* Bh = (const bf16x8*)(wg1h + (size_t)(wave * 16 + r) * 64 + kg * 8);
        const bf16x8* Bl = (const bf16x8*)(wg1l + (size_t)(wave * 16 + r) * 64 + kg * 8);
        bf16x8 ah0 = *(const bf16x8*)&Ah[r][kg * 8];
        bf16x8 ah1 = *(const bf16x8*)&Ah[r][kg * 8 + 32];
        bf16x8 al0 = *(const bf16x8*)&Al[r][kg * 8];
        bf16x8 al1 = *(const bf16x8*)&Al[r][kg * 8 + 32];
        f32x4 acc = {0.f, 0.f, 0.f, 0.f};
        acc = __builtin_amdgcn_mfma_f32_16x16x32_bf16(ah0, Bh[0], acc, 0, 0, 0);
        acc = __builtin_amdgcn_mfma_f32_16x16x32_bf16(ah1, Bh[4], acc, 0, 0, 0);
        acc = __builtin_amdgcn_mfma_f32_16x16x32_bf16(ah0, Bl[0], acc, 0, 0, 0);
        acc = __builtin_amdgcn_mfma_f32_16x16x32_bf16(ah1, Bl[4], acc, 0, 0, 0);
        acc = __builtin_amdgcn_mfma_f32_16x16x32_bf16(al0, Bh[0], acc, 0, 0, 0);
        acc = __builtin_amdgcn_mfma_f32_16x16x32_bf16(al1, Bh[4], acc, 0, 0, 0);
        int col = wave * 16 + r;
        float wg2 = Wg2[col], bb = bg1[col];
        float part[4];
        #pragma unroll
        for (int j = 0; j < 4; ++j) part[j] = fmaxf(acc[j] + bb, 0.f) * wg2;
        #pragma unroll
        for (int o = 8; o > 0; o >>= 1) {
            #pragma unroll
            for (int j = 0; j < 4; ++j) part[j] += __shfl_xor(part[j], o);
        }
        if (r == 0) {
            #pragma unroll
            for (int j = 0; j < 4; ++j) gp[wave][kg * 4 + j] = part[j];
        }
    }
    __syncthreads();
    if (threadIdx.x < 16)
        gate[blockIdx.x * 16 + threadIdx.x] = gp[0][threadIdx.x] + gp[1][threadIdx.x]
                                            + gp[2][threadIdx.x] + gp[3][threadIdx.x] + bg2[0];
}

// ---- per-graph softmax + weighted aggregation (1024 threads) ----
__global__ __launch_bounds__(1024)
void k_final(const float* __restrict__ gate, const float* __restrict__ hfin,
             const int* __restrict__ batch, float* __restrict__ out) {
    __shared__ float red[16];
    __shared__ float redc[16][64];
    int g = blockIdx.x;
    int lo = lbound(batch, N_NODES, g);
    int hi = lbound(batch, N_NODES, g + 1);
    int tid = threadIdx.x, wave = tid >> 6, lane = tid & 63;

    float m = -INFINITY;
    for (int i = lo + tid; i < hi; i += 1024) m = fmaxf(m, gate[i]);
    for (int o = 32; o > 0; o >>= 1) m = fmaxf(m, __shfl_xor(m, o));
    if (lane == 0) red[wave] = m;
    __syncthreads();
    m = -INFINITY;
    #pragma unroll
    for (int i = 0; i < 16; ++i) m = fmaxf(m, red[i]);
    __syncthreads();

    float s = 0.f;
    for (int i = lo + tid; i < hi; i += 1024) s += expf(gate[i] - m);
    for (int o = 32; o > 0; o >>= 1) s += __shfl_xor(s, o);
    if (lane == 0) red[wave] = s;
    __syncthreads();
    s = 0.f;
    #pragma unroll
    for (int i = 0; i < 16; ++i) s += red[i];

    float acc = 0.f;
    for (int i = lo + wave; i < hi; i += 16)
        acc = fmaf(expf(gate[i] - m), hfin[(size_t)i * 64 + lane], acc);
    redc[wave][lane] = acc;
    __syncthreads();
    if (tid < 64) {
        float r = 0.f;
        #pragma unroll
        for (int i = 0; i < 16; ++i) r += redc[i][tid];
        out[g * 64 + tid] = r / (s + EPS);
    }
}

extern "C" void kernel_launch(void* const* d_in, const int* in_sizes, int n_in,
                              void* d_out, int out_size, void* d_ws, size_t ws_size,
                              hipStream_t stream) {
    const float* x    = (const float*)d_in[0];
    const int*   ei   = (const int*)d_in[1];
    const int*   batch= (const int*)d_in[2];
    const float* W1   = (const float*)d_in[3];
    const float* as1  = (const float*)d_in[4];
    const float* ad1  = (const float*)d_in[5];
    const float* b1   = (const float*)d_in[6];
    const float* W2   = (const float*)d_in[7];
    const float* as2  = (const float*)d_in[8];
    const float* ad2  = (const float*)d_in[9];
    const float* b2   = (const float*)d_in[10];
    const float* Wg1  = (const float*)d_in[11];
    const float* bg1  = (const float*)d_in[12];
    const float* Wg2  = (const float*)d_in[13];
    const float* bg2  = (const float*)d_in[14];
    float* out = (float*)d_out;

    char* W = (char*)d_ws;
    size_t off = 0;
    unsigned* cnt = (unsigned*)(W + off); off += (size_t)N_NODES * 4;
    unsigned short* ell  = (unsigned short*)(W + off); off += (size_t)N_NODES * MAX_DEG * 2;
    unsigned short* h1b  = (unsigned short*)(W + off); off += (size_t)N_NODES * 256 * 2;
    float* a_src1 = (float*)(W + off); off += (size_t)N_NODES * HEADS * 4;
    float* a_dst1 = (float*)(W + off); off += (size_t)N_NODES * HEADS * 4;
    float* a_src2 = (float*)(W + off); off += (size_t)N_NODES * 4;
    float* a_dst2 = (float*)(W + off); off += (size_t)N_NODES * 4;
    float* out2   = (float*)(W + off); off += (size_t)N_NODES * HID * 4;
    float* gate   = (float*)(W + off); off += (size_t)N_NODES * 4;
    unsigned short* W1t = (unsigned short*)(W + off); off += (size_t)128 * 256 * 2;
    float* v1s = (float*)(W + off); off += 512 * 4;
    float* v1d = (float*)(W + off); off += 512 * 4;
    unsigned short* W2t = (unsigned short*)(W + off); off += (size_t)64 * 256 * 2;
    float* v2s = (float*)(W + off); off += 256 * 4;
    float* v2d = (float*)(W + off); off += 256 * 4;
    unsigned short* wg1h = (unsigned short*)(W + off); off += (size_t)64 * 64 * 2;
    unsigned short* wg1l = (unsigned short*)(W + off); off += (size_t)64 * 64 * 2;
    unsigned short* h2b = (unsigned short*)(W + off); off += (size_t)N_NODES * HID * 2;
    (void)ws_size; (void)in_sizes; (void)n_in; (void)out_size;

    // 1: ELL build (scan-based, no global atomics, self-zeroing)
    k_ell2<<<ELL_NB, 1024, 0, stream>>>(ei, cnt, ell);
    // 2: weights prep
    k_wprep<<<51, 256, 0, stream>>>(W1, as1, ad1, W2, as2, ad2, Wg1,
                                    W1t, v1s, v1d, W2t, v2s, v2d, wg1h, wg1l);
    // 3: layer 1 GEMM (+ logit dots)
    k_gemm1_mfma<<<N_NODES / 16, 256, 0, stream>>>(x, W1t, v1s, v1d, h1b, a_src1, a_dst1);
    // 4: node1 gather + gemm2
    k_layer1<<<N_NODES / 16, 1024, 0, stream>>>(ell, cnt, (const float4*)a_src1,
        (const float4*)a_dst1, h1b, (const float4*)b1,
        (const float4*)v2s, (const float4*)v2d, W2t, a_src2, a_dst2, h2b);
    // 5: node2 gather + gate MLP
    k_layer2<<<N_NODES / 16, 1024, 0, stream>>>(ell, cnt, a_src2, a_dst2, h2b, b2,
                                                wg1h, wg1l, bg1, Wg2, bg2, out2, gate);
    // 6: per-graph softmax aggregation
    k_final<<<N_GRAPHS, 1024, 0, stream>>>(gate, out2, batch, out);
}

// Round 17
// 294.127 us; speedup vs baseline: 1.9715x; 1.9715x over previous
//
#include <hip/hip_runtime.h>
#include <math.h>

#define N_NODES 50000
#define N_EDGES 800000
#define E_TOT   850000
#define N_GRAPHS 64
#define EMB 128
#define HID 64
#define HEADS 4
#define NEG_SLOPE 0.2f
#define EPS 1e-16f
#define MAX_DEG 64
#define SUB_CAP 20
#define G1_TILES (N_NODES / 16)
#define ELL_BLKS ((E_TOT + 255) / 256)

typedef short bf16x8 __attribute__((ext_vector_type(8)));
typedef float f32x4  __attribute__((ext_vector_type(4)));

__device__ __forceinline__ float leaky(float x) { return x >= 0.f ? x : NEG_SLOPE * x; }
__device__ __forceinline__ float elu(float x)   { return x > 0.f ? x : expf(x) - 1.f; }

__device__ __forceinline__ unsigned short f2bf(float f) {
    unsigned u = __float_as_uint(f);
    return (unsigned short)((u + 0x7FFFu + ((u >> 16) & 1u)) >> 16);
}
__device__ __forceinline__ float bf2f(unsigned short h) {
    return __uint_as_float((unsigned)h << 16);
}

__device__ __forceinline__ void edge_sd(const int* __restrict__ ei, int e, int& s, int& d) {
    if (e < N_EDGES) { s = ei[e]; d = ei[N_EDGES + e]; }
    else             { s = d = e - N_EDGES; }
}

__device__ __forceinline__ int lbound(const int* __restrict__ a, int n, int v) {
    int lo = 0, hi = n;
    while (lo < hi) { int mid = (lo + hi) >> 1; if (a[mid] < v) lo = mid + 1; else hi = mid; }
    return lo;
}

// ---- weight prep + cnt4 zero (blocks 51-63) ----
__global__ void k_wprep(const float* __restrict__ W1, const float* __restrict__ as1, const float* __restrict__ ad1,
                        const float* __restrict__ W2, const float* __restrict__ as2, const float* __restrict__ ad2,
                        const float* __restrict__ Wg1,
                        unsigned short* __restrict__ W1t, float* __restrict__ v1s, float* __restrict__ v1d,
                        unsigned short* __restrict__ W2t, float* __restrict__ v2s, float* __restrict__ v2d,
                        unsigned short* __restrict__ wg1h, unsigned short* __restrict__ wg1l,
                        unsigned* __restrict__ cnt4) {
    int b = blockIdx.x, t = threadIdx.x;
    if (b < 32) {
        for (int i = b * 1024 + t; i < (b + 1) * 1024; i += 256) {
            int c = i >> 7, k = i & 127;
            W1t[i] = f2bf(W1[k * 256 + c]);
        }
    } else if (b < 48) {
        int bb = b - 32;
        for (int i = bb * 1024 + t; i < (bb + 1) * 1024; i += 256) {
            int c = i >> 8, k = i & 255;
            W2t[i] = f2bf(W2[k * 64 + c]);
        }
    } else if (b == 48) {
        for (int i = t; i < 512; i += 256) {
            int h = i >> 7, k = i & 127;
            float s = 0.f, d = 0.f;
            for (int c = 0; c < 64; ++c) {
                float wv = W1[k * 256 + h * 64 + c];
                s = fmaf(wv, as1[h * 64 + c], s);
                d = fmaf(wv, ad1[h * 64 + c], d);
            }
            v1s[i] = s; v1d[i] = d;
        }
    } else if (b == 49) {
        float s = 0.f, d = 0.f;
        for (int cc = 0; cc < 64; ++cc) {
            float wv = W2[t * 64 + cc];
            s = fmaf(wv, as2[cc], s);
            d = fmaf(wv, ad2[cc], d);
        }
        v2s[t] = s; v2d[t] = d;
    } else if (b == 50) {
        for (int i = t; i < 4096; i += 256) {
            int c = i >> 6, k = i & 63;
            float v = Wg1[k * 64 + c];
            unsigned short h = f2bf(v);
            wg1h[i] = h;
            wg1l[i] = f2bf(v - bf2f(h));
        }
    } else {                                        // blocks 51-63: zero cnt4
        for (int i = (b - 51) * 256 + t; i < 4 * N_NODES; i += 13 * 256) cnt4[i] = 0;
    }
}

// ---- FUSED: gemm1 MFMA (+logit dots) [blocks < G1_TILES] | ELL4 build [rest] ----
// ELL4: edge e uses sub-counter e&3 -> 4x fewer same-address atomic chains
__global__ __launch_bounds__(256)
void k_prep2(const float* __restrict__ x, const unsigned short* __restrict__ W1t,
             const float* __restrict__ v1s, const float* __restrict__ v1d,
             unsigned short* __restrict__ h1b, float* __restrict__ a_src1,
             float* __restrict__ a_dst1,
             const int* __restrict__ ei, unsigned* __restrict__ cnt4,
             unsigned short* __restrict__ ell4) {
    if (blockIdx.x >= G1_TILES) {
        int e = (blockIdx.x - G1_TILES) * 256 + threadIdx.x;
        if (e < E_TOT) {
            int s, d; edge_sd(ei, e, s, d);
            int sub = e & 3;
            unsigned slot = atomicAdd(&cnt4[sub * N_NODES + d], 1u);
            if (slot < SUB_CAP)
                ell4[(size_t)d * (4 * SUB_CAP) + sub * SUB_CAP + slot] = (unsigned short)s;
        }
        return;
    }
    int w = threadIdx.x >> 6, l = threadIdx.x & 63;
    int r = l & 15, kg = l >> 4;
    int tile = blockIdx.x;
    const float* xr = x + (size_t)(tile * 16 + r) * 128 + kg * 8;
    bf16x8 af[4];
    float ps = 0.f, pd = 0.f;
    #pragma unroll
    for (int j = 0; j < 4; ++j) {
        float4 f0 = *(const float4*)(xr + j * 32);
        float4 f1 = *(const float4*)(xr + j * 32 + 4);
        const float* vs = v1s + w * 128 + j * 32 + kg * 8;
        const float* vd = v1d + w * 128 + j * 32 + kg * 8;
        float4 s0 = *(const float4*)vs, s1 = *(const float4*)(vs + 4);
        float4 d0 = *(const float4*)vd, d1 = *(const float4*)(vd + 4);
        ps += f0.x*s0.x + f0.y*s0.y + f0.z*s0.z + f0.w*s0.w
            + f1.x*s1.x + f1.y*s1.y + f1.z*s1.z + f1.w*s1.w;
        pd += f0.x*d0.x + f0.y*d0.y + f0.z*d0.z + f0.w*d0.w
            + f1.x*d1.x + f1.y*d1.y + f1.z*d1.z + f1.w*d1.w;
        bf16x8 t;
        t[0] = (short)f2bf(f0.x); t[1] = (short)f2bf(f0.y);
        t[2] = (short)f2bf(f0.z); t[3] = (short)f2bf(f0.w);
        t[4] = (short)f2bf(f1.x); t[5] = (short)f2bf(f1.y);
        t[6] = (short)f2bf(f1.z); t[7] = (short)f2bf(f1.w);
        af[j] = t;
    }
    ps += __shfl_xor(ps, 16); ps += __shfl_xor(ps, 32);
    pd += __shfl_xor(pd, 16); pd += __shfl_xor(pd, 32);
    if (l < 16) {
        a_src1[(size_t)(tile * 16 + r) * 4 + w] = ps;
        a_dst1[(size_t)(tile * 16 + r) * 4 + w] = pd;
    }
    for (int cc = 0; cc < 4; ++cc) {
        int c0 = cc * 64 + w * 16;
        const bf16x8* B = (const bf16x8*)(W1t + (size_t)(c0 + r) * 128 + kg * 8);
        f32x4 acc = {0.f, 0.f, 0.f, 0.f};
        acc = __builtin_amdgcn_mfma_f32_16x16x32_bf16(af[0], B[0],  acc, 0, 0, 0);
        acc = __builtin_amdgcn_mfma_f32_16x16x32_bf16(af[1], B[4],  acc, 0, 0, 0);
        acc = __builtin_amdgcn_mfma_f32_16x16x32_bf16(af[2], B[8],  acc, 0, 0, 0);
        acc = __builtin_amdgcn_mfma_f32_16x16x32_bf16(af[3], B[12], acc, 0, 0, 0);
        #pragma unroll
        for (int j = 0; j < 4; ++j)
            h1b[(size_t)(tile * 16 + kg * 4 + j) * 256 + c0 + r] = f2bf(acc[j]);
    }
}

// ---- compact ELL4 -> ELL (thread per node) ----
__global__ __launch_bounds__(256)
void k_compact(const unsigned* __restrict__ cnt4, const unsigned short* __restrict__ ell4,
               unsigned* __restrict__ cnt, unsigned short* __restrict__ ell) {
    int n = blockIdx.x * 256 + threadIdx.x;
    if (n >= N_NODES) return;
    int pos = 0;
    #pragma unroll
    for (int sub = 0; sub < 4; ++sub) {
        int c = min((int)cnt4[sub * N_NODES + n], SUB_CAP);
        for (int k = 0; k < c; ++k) {
            if (pos < MAX_DEG)
                ell[(size_t)n * MAX_DEG + pos] = ell4[(size_t)n * (4 * SUB_CAP) + sub * SUB_CAP + k];
            ++pos;
        }
    }
    cnt[n] = min(pos, MAX_DEG);
}

// ---- FUSED layer 1: node gather (pipelined) + softmax + ELU, then gemm2 MFMA in-block ----
__global__ __launch_bounds__(1024)
void k_layer1(const unsigned short* __restrict__ ell, const unsigned* __restrict__ cnt,
              const float4* __restrict__ asrc, const float4* __restrict__ adst,
              const unsigned short* __restrict__ h1b, const float4* __restrict__ bias,
              const float4* __restrict__ v2s4, const float4* __restrict__ v2d4,
              const unsigned short* __restrict__ W2t,
              float* __restrict__ a_src2, float* __restrict__ a_dst2,
              unsigned short* __restrict__ h2b) {
    __shared__ float sw[4][16][65];
    __shared__ int   ss[16][MAX_DEG];
    __shared__ unsigned short Ash[16][264];
    int wave = threadIdx.x >> 6, lane = threadIdx.x & 63;
    int node = blockIdx.x * 16 + wave;
    int deg = min((int)cnt[node], MAX_DEG);

    float4 ad = adst[node];
    float a0 = -INFINITY, a1 = -INFINITY, a2 = -INFINITY, a3 = -INFINITY;
    int s = 0;
    if (lane < deg) {
        s = ell[node * MAX_DEG + lane];
        float4 as = asrc[s];
        a0 = leaky(as.x + ad.x); a1 = leaky(as.y + ad.y);
        a2 = leaky(as.z + ad.z); a3 = leaky(as.w + ad.w);
    }
    float m0 = a0, m1 = a1, m2 = a2, m3 = a3;
    for (int o = 32; o > 0; o >>= 1) {
        m0 = fmaxf(m0, __shfl_xor(m0, o)); m1 = fmaxf(m1, __shfl_xor(m1, o));
        m2 = fmaxf(m2, __shfl_xor(m2, o)); m3 = fmaxf(m3, __shfl_xor(m3, o));
    }
    float w0 = lane < deg ? expf(a0 - m0) : 0.f;
    float w1 = lane < deg ? expf(a1 - m1) : 0.f;
    float w2 = lane < deg ? expf(a2 - m2) : 0.f;
    float w3 = lane < deg ? expf(a3 - m3) : 0.f;
    float t0 = w0, t1 = w1, t2 = w2, t3 = w3;
    for (int o = 32; o > 0; o >>= 1) {
        t0 += __shfl_xor(t0, o); t1 += __shfl_xor(t1, o);
        t2 += __shfl_xor(t2, o); t3 += __shfl_xor(t3, o);
    }
    w0 /= (t0 + EPS); w1 /= (t1 + EPS); w2 /= (t2 + EPS); w3 /= (t3 + EPS);
    if (lane < deg) {
        sw[0][wave][lane] = w0; sw[1][wave][lane] = w1;
        sw[2][wave][lane] = w2; sw[3][wave][lane] = w3;
        ss[wave][lane] = s;
    }
    int head = lane >> 4;
    float c0 = 0.f, c1 = 0.f, c2 = 0.f, c3 = 0.f;
    ushort4 hcur = *(const ushort4*)(h1b + (size_t)ss[wave][0] * 256 + lane * 4);
    float   wcur = sw[head][wave][0];
    for (int e = 1; e < deg; ++e) {
        ushort4 hnx = *(const ushort4*)(h1b + (size_t)ss[wave][e] * 256 + lane * 4);
        float   wnx = sw[head][wave][e];
        c0 = fmaf(bf2f(hcur.x), wcur, c0); c1 = fmaf(bf2f(hcur.y), wcur, c1);
        c2 = fmaf(bf2f(hcur.z), wcur, c2); c3 = fmaf(bf2f(hcur.w), wcur, c3);
        hcur = hnx; wcur = wnx;
    }
    c0 = fmaf(bf2f(hcur.x), wcur, c0); c1 = fmaf(bf2f(hcur.y), wcur, c1);
    c2 = fmaf(bf2f(hcur.z), wcur, c2); c3 = fmaf(bf2f(hcur.w), wcur, c3);

    float4 b = bias[lane];
    float o0 = elu(c0 + b.x), o1 = elu(c1 + b.y), o2 = elu(c2 + b.z), o3 = elu(c3 + b.w);
    *(ushort4*)&Ash[wave][lane * 4] = make_ushort4(f2bf(o0), f2bf(o1), f2bf(o2), f2bf(o3));
    float4 vs = v2s4[lane], vd = v2d4[lane];
    float ps = o0 * vs.x + o1 * vs.y + o2 * vs.z + o3 * vs.w;
    float pd = o0 * vd.x + o1 * vd.y + o2 * vd.z + o3 * vd.w;
    for (int o = 32; o > 0; o >>= 1) { ps += __shfl_xor(ps, o); pd += __shfl_xor(pd, o); }
    if (lane == 0) { a_src2[node] = ps; a_dst2[node] = pd; }

    __syncthreads();
    if (wave < 4) {
        int r = lane & 15, kg = lane >> 4;
        f32x4 acc = {0.f, 0.f, 0.f, 0.f};
        #pragma unroll
        for (int kk = 0; kk < 8; ++kk) {
            bf16x8 afr = *(const bf16x8*)&Ash[r][kg * 8 + kk * 32];
            bf16x8 bfr = *(const bf16x8*)(W2t + (size_t)(wave * 16 + r) * 256 + kg * 8 + kk * 32);
            acc = __builtin_amdgcn_mfma_f32_16x16x32_bf16(afr, bfr, acc, 0, 0, 0);
        }
        #pragma unroll
        for (int j = 0; j < 4; ++j)
            h2b[(size_t)(blockIdx.x * 16 + kg * 4 + j) * 64 + wave * 16 + r] = f2bf(acc[j]);
    }
}

// ---- FUSED layer 2: node gather (pipelined) + gate MFMA in-block ----
__global__ __launch_bounds__(1024)
void k_layer2(const unsigned short* __restrict__ ell, const unsigned* __restrict__ cnt,
              const float* __restrict__ asrc, const float* __restrict__ adst,
              const unsigned short* __restrict__ h2b, const float* __restrict__ bias,
              const unsigned short* __restrict__ wg1h, const unsigned short* __restrict__ wg1l,
              const float* __restrict__ bg1, const float* __restrict__ Wg2,
              const float* __restrict__ bg2,
              float* __restrict__ out2, float* __restrict__ gate) {
    __shared__ float sw[16][MAX_DEG];
    __shared__ int   ss[16][MAX_DEG];
    __shared__ unsigned short Ah[16][72], Al[16][72];
    __shared__ float gp[4][16];
    int wave = threadIdx.x >> 6, lane = threadIdx.x & 63;
    int half = lane >> 5, li = lane & 31;
    int node = blockIdx.x * 16 + wave;
    int deg = min((int)cnt[node], MAX_DEG);

    float adv = adst[node];
    float a = -INFINITY;
    int s = 0;
    if (lane < deg) {
        s = ell[node * MAX_DEG + lane];
        a = leaky(asrc[s] + adv);
    }
    float m = a;
    for (int o = 32; o > 0; o >>= 1) m = fmaxf(m, __shfl_xor(m, o));
    float w = lane < deg ? expf(a - m) : 0.f;
    float t = w;
    for (int o = 32; o > 0; o >>= 1) t += __shfl_xor(t, o);
    w /= (t + EPS);
    if (lane < deg) { sw[wave][lane] = w; ss[wave][lane] = s; }

    float c0 = 0.f, c1 = 0.f;
    int row = half;
    unsigned ucur = 0; float wcur = 0.f;
    if (row < deg) {
        ucur = *(const unsigned*)(h2b + (size_t)ss[wave][row] * 64 + li * 2);
        wcur = sw[wave][row];
    }
    while (row < deg) {
        int nrow = row + 2;
        unsigned unx = 0; float wnx = 0.f;
        if (nrow < deg) {
            unx = *(const unsigned*)(h2b + (size_t)ss[wave][nrow] * 64 + li * 2);
            wnx = sw[wave][nrow];
        }
        c0 = fmaf(__uint_as_float(ucur << 16), wcur, c0);
        c1 = fmaf(__uint_as_float(ucur & 0xffff0000u), wcur, c1);
        ucur = unx; wcur = wnx; row = nrow;
    }
    c0 += __shfl_xor(c0, 32);
    c1 += __shfl_xor(c1, 32);
    if (half == 0) {
        float o0 = elu(c0 + bias[li * 2]);
        float o1 = elu(c1 + bias[li * 2 + 1]);
        *(float2*)(out2 + (size_t)node * 64 + li * 2) = make_float2(o0, o1);
        unsigned short h0 = f2bf(o0), h1 = f2bf(o1);
        *(unsigned*)&Ah[wave][li * 2] = ((unsigned)h1 << 16) | h0;
        unsigned short l0 = f2bf(o0 - bf2f(h0)), l1 = f2bf(o1 - bf2f(h1));
        *(unsigned*)&Al[wave][li * 2] = ((unsigned)l1 << 16) | l0;
    }

    __syncthreads();
    if (wave < 4) {
        int r = lane & 15, kg = lane >> 4;
        const bf16x8* Bh = (const bf16x8*)(wg1h + (size_t)(wave * 16 + r) * 64 + kg * 8);
        const bf16x8* Bl = (const bf16x8*)(wg1l + (size_t)(wave * 16 + r) * 64 + kg * 8);
        bf16x8 ah0 = *(const bf16x8*)&Ah[r][kg * 8];
        bf16x8 ah1 = *(const bf16x8*)&Ah[r][kg * 8 + 32];
        bf16x8 al0 = *(const bf16x8*)&Al[r][kg * 8];
        bf16x8 al1 = *(const bf16x8*)&Al[r][kg * 8 + 32];
        f32x4 acc = {0.f, 0.f, 0.f, 0.f};
        acc = __builtin_amdgcn_mfma_f32_16x16x32_bf16(ah0, Bh[0], acc, 0, 0, 0);
        acc = __builtin_amdgcn_mfma_f32_16x16x32_bf16(ah1, Bh[4], acc, 0, 0, 0);
        acc = __builtin_amdgcn_mfma_f32_16x16x32_bf16(ah0, Bl[0], acc, 0, 0, 0);
        acc = __builtin_amdgcn_mfma_f32_16x16x32_bf16(ah1, Bl[4], acc, 0, 0, 0);
        acc = __builtin_amdgcn_mfma_f32_16x16x32_bf16(al0, Bh[0], acc, 0, 0, 0);
        acc = __builtin_amdgcn_mfma_f32_16x16x32_bf16(al1, Bh[4], acc, 0, 0, 0);
        int col = wave * 16 + r;
        float wg2 = Wg2[col], bb = bg1[col];
        float part[4];
        #pragma unroll
        for (int j = 0; j < 4; ++j) part[j] = fmaxf(acc[j] + bb, 0.f) * wg2;
        #pragma unroll
        for (int o = 8; o > 0; o >>= 1) {
            #pragma unroll
            for (int j = 0; j < 4; ++j) part[j] += __shfl_xor(part[j], o);
        }
        if (r == 0) {
            #pragma unroll
            for (int j = 0; j < 4; ++j) gp[wave][kg * 4 + j] = part[j];
        }
    }
    __syncthreads();
    if (threadIdx.x < 16)
        gate[blockIdx.x * 16 + threadIdx.x] = gp[0][threadIdx.x] + gp[1][threadIdx.x]
                                            + gp[2][threadIdx.x] + gp[3][threadIdx.x] + bg2[0];
}

// ---- per-graph softmax + weighted aggregation (1024 threads) ----
__global__ __launch_bounds__(1024)
void k_final(const float* __restrict__ gate, const float* __restrict__ hfin,
             const int* __restrict__ batch, float* __restrict__ out) {
    __shared__ float red[16];
    __shared__ float redc[16][64];
    int g = blockIdx.x;
    int lo = lbound(batch, N_NODES, g);
    int hi = lbound(batch, N_NODES, g + 1);
    int tid = threadIdx.x, wave = tid >> 6, lane = tid & 63;

    float m = -INFINITY;
    for (int i = lo + tid; i < hi; i += 1024) m = fmaxf(m, gate[i]);
    for (int o = 32; o > 0; o >>= 1) m = fmaxf(m, __shfl_xor(m, o));
    if (lane == 0) red[wave] = m;
    __syncthreads();
    m = -INFINITY;
    #pragma unroll
    for (int i = 0; i < 16; ++i) m = fmaxf(m, red[i]);
    __syncthreads();

    float s = 0.f;
    for (int i = lo + tid; i < hi; i += 1024) s += expf(gate[i] - m);
    for (int o = 32; o > 0; o >>= 1) s += __shfl_xor(s, o);
    if (lane == 0) red[wave] = s;
    __syncthreads();
    s = 0.f;
    #pragma unroll
    for (int i = 0; i < 16; ++i) s += red[i];

    float acc = 0.f;
    for (int i = lo + wave; i < hi; i += 16)
        acc = fmaf(expf(gate[i] - m), hfin[(size_t)i * 64 + lane], acc);
    redc[wave][lane] = acc;
    __syncthreads();
    if (tid < 64) {
        float r = 0.f;
        #pragma unroll
        for (int i = 0; i < 16; ++i) r += redc[i][tid];
        out[g * 64 + tid] = r / (s + EPS);
    }
}

extern "C" void kernel_launch(void* const* d_in, const int* in_sizes, int n_in,
                              void* d_out, int out_size, void* d_ws, size_t ws_size,
                              hipStream_t stream) {
    const float* x    = (const float*)d_in[0];
    const int*   ei   = (const int*)d_in[1];
    const int*   batch= (const int*)d_in[2];
    const float* W1   = (const float*)d_in[3];
    const float* as1  = (const float*)d_in[4];
    const float* ad1  = (const float*)d_in[5];
    const float* b1   = (const float*)d_in[6];
    const float* W2   = (const float*)d_in[7];
    const float* as2  = (const float*)d_in[8];
    const float* ad2  = (const float*)d_in[9];
    const float* b2   = (const float*)d_in[10];
    const float* Wg1  = (const float*)d_in[11];
    const float* bg1  = (const float*)d_in[12];
    const float* Wg2  = (const float*)d_in[13];
    const float* bg2  = (const float*)d_in[14];
    float* out = (float*)d_out;

    char* W = (char*)d_ws;
    size_t off = 0;
    unsigned* cnt  = (unsigned*)(W + off); off += (size_t)N_NODES * 4;
    unsigned* cnt4 = (unsigned*)(W + off); off += (size_t)4 * N_NODES * 4;                   // 800 KB
    unsigned short* ell  = (unsigned short*)(W + off); off += (size_t)N_NODES * MAX_DEG * 2; // 6.4 MB
    unsigned short* ell4 = (unsigned short*)(W + off); off += (size_t)N_NODES * 4 * SUB_CAP * 2; // 8 MB
    unsigned short* h1b  = (unsigned short*)(W + off); off += (size_t)N_NODES * 256 * 2;     // 25.6 MB
    float* a_src1 = (float*)(W + off); off += (size_t)N_NODES * HEADS * 4;
    float* a_dst1 = (float*)(W + off); off += (size_t)N_NODES * HEADS * 4;
    float* a_src2 = (float*)(W + off); off += (size_t)N_NODES * 4;
    float* a_dst2 = (float*)(W + off); off += (size_t)N_NODES * 4;
    float* out2   = (float*)(W + off); off += (size_t)N_NODES * HID * 4;                     // 12.8 MB
    float* gate   = (float*)(W + off); off += (size_t)N_NODES * 4;
    unsigned short* W1t = (unsigned short*)(W + off); off += (size_t)128 * 256 * 2;
    float* v1s = (float*)(W + off); off += 512 * 4;
    float* v1d = (float*)(W + off); off += 512 * 4;
    unsigned short* W2t = (unsigned short*)(W + off); off += (size_t)64 * 256 * 2;
    float* v2s = (float*)(W + off); off += 256 * 4;
    float* v2d = (float*)(W + off); off += 256 * 4;
    unsigned short* wg1h = (unsigned short*)(W + off); off += (size_t)64 * 64 * 2;
    unsigned short* wg1l = (unsigned short*)(W + off); off += (size_t)64 * 64 * 2;
    unsigned short* h2b = (unsigned short*)(W + off); off += (size_t)N_NODES * HID * 2;      // 6.4 MB
    (void)ws_size; (void)in_sizes; (void)n_in; (void)out_size;

    // 1: weights prep + cnt4 zero
    k_wprep<<<64, 256, 0, stream>>>(W1, as1, ad1, W2, as2, ad2, Wg1,
                                    W1t, v1s, v1d, W2t, v2s, v2d, wg1h, wg1l, cnt4);
    // 2: gemm1 (+logit dots) | ELL4 build (4-way diluted atomics)
    k_prep2<<<G1_TILES + ELL_BLKS, 256, 0, stream>>>(x, W1t, v1s, v1d, h1b, a_src1, a_dst1,
                                                     ei, cnt4, ell4);
    // 3: compact ELL4 -> ELL
    k_compact<<<(N_NODES + 255) / 256, 256, 0, stream>>>(cnt4, ell4, cnt, ell);
    // 4: node1 gather + gemm2
    k_layer1<<<N_NODES / 16, 1024, 0, stream>>>(ell, cnt, (const float4*)a_src1,
        (const float4*)a_dst1, h1b, (const float4*)b1,
        (const float4*)v2s, (const float4*)v2d, W2t, a_src2, a_dst2, h2b);
    // 5: node2 gather + gate MLP
    k_layer2<<<N_NODES / 16, 1024, 0, stream>>>(ell, cnt, a_src2, a_dst2, h2b, b2,
                                                wg1h, wg1l, bg1, Wg2, bg2, out2, gate);
    // 6: per-graph softmax aggregation
    k_final<<<N_GRAPHS, 1024, 0, stream>>>(gate, out2, batch, out);
}

// Round 18
// 277.967 us; speedup vs baseline: 2.0861x; 1.0581x over previous
//
#include <hip/hip_runtime.h>
#include <math.h>

#define N_NODES 50000
#define N_EDGES 800000
#define E_TOT   850000
#define N_GRAPHS 64
#define EMB 128
#define HID 64
#define HEADS 4
#define NEG_SLOPE 0.2f
#define EPS 1e-16f
#define MAX_DEG 64
#define CNT_STRIDE 32            // 128B per counter: one L2 line each
#define G1_TILES (N_NODES / 16)
#define ELL_BLKS ((E_TOT + 255) / 256)

typedef short bf16x8 __attribute__((ext_vector_type(8)));
typedef float f32x4  __attribute__((ext_vector_type(4)));

__device__ __forceinline__ float leaky(float x) { return x >= 0.f ? x : NEG_SLOPE * x; }
__device__ __forceinline__ float elu(float x)   { return x > 0.f ? x : expf(x) - 1.f; }

__device__ __forceinline__ unsigned short f2bf(float f) {
    unsigned u = __float_as_uint(f);
    return (unsigned short)((u + 0x7FFFu + ((u >> 16) & 1u)) >> 16);
}
__device__ __forceinline__ float bf2f(unsigned short h) {
    return __uint_as_float((unsigned)h << 16);
}

__device__ __forceinline__ void edge_sd(const int* __restrict__ ei, int e, int& s, int& d) {
    if (e < N_EDGES) { s = ei[e]; d = ei[N_EDGES + e]; }
    else             { s = d = e - N_EDGES; }
}

__device__ __forceinline__ int lbound(const int* __restrict__ a, int n, int v) {
    int lo = 0, hi = n;
    while (lo < hi) { int mid = (lo + hi) >> 1; if (a[mid] < v) lo = mid + 1; else hi = mid; }
    return lo;
}

// ---- weight prep + cnt_pad zero (blocks 51-95) ----
__global__ void k_wprep(const float* __restrict__ W1, const float* __restrict__ as1, const float* __restrict__ ad1,
                        const float* __restrict__ W2, const float* __restrict__ as2, const float* __restrict__ ad2,
                        const float* __restrict__ Wg1,
                        unsigned short* __restrict__ W1t, float* __restrict__ v1s, float* __restrict__ v1d,
                        unsigned short* __restrict__ W2t, float* __restrict__ v2s, float* __restrict__ v2d,
                        unsigned short* __restrict__ wg1h, unsigned short* __restrict__ wg1l,
                        uint4* __restrict__ cnt_pad4) {
    int b = blockIdx.x, t = threadIdx.x;
    if (b < 32) {
        for (int i = b * 1024 + t; i < (b + 1) * 1024; i += 256) {
            int c = i >> 7, k = i & 127;
            W1t[i] = f2bf(W1[k * 256 + c]);
        }
    } else if (b < 48) {
        int bb = b - 32;
        for (int i = bb * 1024 + t; i < (bb + 1) * 1024; i += 256) {
            int c = i >> 8, k = i & 255;
            W2t[i] = f2bf(W2[k * 64 + c]);
        }
    } else if (b == 48) {
        for (int i = t; i < 512; i += 256) {
            int h = i >> 7, k = i & 127;
            float s = 0.f, d = 0.f;
            for (int c = 0; c < 64; ++c) {
                float wv = W1[k * 256 + h * 64 + c];
                s = fmaf(wv, as1[h * 64 + c], s);
                d = fmaf(wv, ad1[h * 64 + c], d);
            }
            v1s[i] = s; v1d[i] = d;
        }
    } else if (b == 49) {
        float s = 0.f, d = 0.f;
        for (int cc = 0; cc < 64; ++cc) {
            float wv = W2[t * 64 + cc];
            s = fmaf(wv, as2[cc], s);
            d = fmaf(wv, ad2[cc], d);
        }
        v2s[t] = s; v2d[t] = d;
    } else if (b == 50) {
        for (int i = t; i < 4096; i += 256) {
            int c = i >> 6, k = i & 63;
            float v = Wg1[k * 64 + c];
            unsigned short h = f2bf(v);
            wg1h[i] = h;
            wg1l[i] = f2bf(v - bf2f(h));
        }
    } else {                      // blocks 51-95: zero cnt_pad (50000*32 words = 400000 uint4)
        const int total4 = N_NODES * CNT_STRIDE / 4;
        for (int i = (b - 51) * 256 + t; i < total4; i += 45 * 256)
            cnt_pad4[i] = make_uint4(0, 0, 0, 0);
    }
}

// ---- FUSED: gemm1 MFMA (+logit dots) [blocks < G1_TILES] | ELL build [rest] ----
// counters padded to one line each -> per-line serialized atomic hits drop 68 -> 17
__global__ __launch_bounds__(256)
void k_prep2(const float* __restrict__ x, const unsigned short* __restrict__ W1t,
             const float* __restrict__ v1s, const float* __restrict__ v1d,
             unsigned short* __restrict__ h1b, float* __restrict__ a_src1,
             float* __restrict__ a_dst1,
             const int* __restrict__ ei, unsigned* __restrict__ cnt_pad,
             unsigned short* __restrict__ ell) {
    if (blockIdx.x >= G1_TILES) {
        int e = (blockIdx.x - G1_TILES) * 256 + threadIdx.x;
        if (e < E_TOT) {
            int s, d; edge_sd(ei, e, s, d);
            unsigned slot = atomicAdd(&cnt_pad[(size_t)d * CNT_STRIDE], 1u);
            if (slot < MAX_DEG)
                ell[(size_t)d * MAX_DEG + slot] = (unsigned short)s;
        }
        return;
    }
    int w = threadIdx.x >> 6, l = threadIdx.x & 63;
    int r = l & 15, kg = l >> 4;
    int tile = blockIdx.x;
    const float* xr = x + (size_t)(tile * 16 + r) * 128 + kg * 8;
    bf16x8 af[4];
    float ps = 0.f, pd = 0.f;
    #pragma unroll
    for (int j = 0; j < 4; ++j) {
        float4 f0 = *(const float4*)(xr + j * 32);
        float4 f1 = *(const float4*)(xr + j * 32 + 4);
        const float* vs = v1s + w * 128 + j * 32 + kg * 8;
        const float* vd = v1d + w * 128 + j * 32 + kg * 8;
        float4 s0 = *(const float4*)vs, s1 = *(const float4*)(vs + 4);
        float4 d0 = *(const float4*)vd, d1 = *(const float4*)(vd + 4);
        ps += f0.x*s0.x + f0.y*s0.y + f0.z*s0.z + f0.w*s0.w
            + f1.x*s1.x + f1.y*s1.y + f1.z*s1.z + f1.w*s1.w;
        pd += f0.x*d0.x + f0.y*d0.y + f0.z*d0.z + f0.w*d0.w
            + f1.x*d1.x + f1.y*d1.y + f1.z*d1.z + f1.w*d1.w;
        bf16x8 t;
        t[0] = (short)f2bf(f0.x); t[1] = (short)f2bf(f0.y);
        t[2] = (short)f2bf(f0.z); t[3] = (short)f2bf(f0.w);
        t[4] = (short)f2bf(f1.x); t[5] = (short)f2bf(f1.y);
        t[6] = (short)f2bf(f1.z); t[7] = (short)f2bf(f1.w);
        af[j] = t;
    }
    ps += __shfl_xor(ps, 16); ps += __shfl_xor(ps, 32);
    pd += __shfl_xor(pd, 16); pd += __shfl_xor(pd, 32);
    if (l < 16) {
        a_src1[(size_t)(tile * 16 + r) * 4 + w] = ps;
        a_dst1[(size_t)(tile * 16 + r) * 4 + w] = pd;
    }
    for (int cc = 0; cc < 4; ++cc) {
        int c0 = cc * 64 + w * 16;
        const bf16x8* B = (const bf16x8*)(W1t + (size_t)(c0 + r) * 128 + kg * 8);
        f32x4 acc = {0.f, 0.f, 0.f, 0.f};
        acc = __builtin_amdgcn_mfma_f32_16x16x32_bf16(af[0], B[0],  acc, 0, 0, 0);
        acc = __builtin_amdgcn_mfma_f32_16x16x32_bf16(af[1], B[4],  acc, 0, 0, 0);
        acc = __builtin_amdgcn_mfma_f32_16x16x32_bf16(af[2], B[8],  acc, 0, 0, 0);
        acc = __builtin_amdgcn_mfma_f32_16x16x32_bf16(af[3], B[12], acc, 0, 0, 0);
        #pragma unroll
        for (int j = 0; j < 4; ++j)
            h1b[(size_t)(tile * 16 + kg * 4 + j) * 256 + c0 + r] = f2bf(acc[j]);
    }
}

// ---- FUSED layer 1: node gather (pipelined) + softmax + ELU, then gemm2 MFMA in-block ----
__global__ __launch_bounds__(1024)
void k_layer1(const unsigned short* __restrict__ ell, const unsigned* __restrict__ cnt_pad,
              const float4* __restrict__ asrc, const float4* __restrict__ adst,
              const unsigned short* __restrict__ h1b, const float4* __restrict__ bias,
              const float4* __restrict__ v2s4, const float4* __restrict__ v2d4,
              const unsigned short* __restrict__ W2t,
              float* __restrict__ a_src2, float* __restrict__ a_dst2,
              unsigned short* __restrict__ h2b) {
    __shared__ float sw[4][16][65];
    __shared__ int   ss[16][MAX_DEG];
    __shared__ unsigned short Ash[16][264];
    int wave = threadIdx.x >> 6, lane = threadIdx.x & 63;
    int node = blockIdx.x * 16 + wave;
    int deg = min((int)cnt_pad[(size_t)node * CNT_STRIDE], MAX_DEG);

    float4 ad = adst[node];
    float a0 = -INFINITY, a1 = -INFINITY, a2 = -INFINITY, a3 = -INFINITY;
    int s = 0;
    if (lane < deg) {
        s = ell[node * MAX_DEG + lane];
        float4 as = asrc[s];
        a0 = leaky(as.x + ad.x); a1 = leaky(as.y + ad.y);
        a2 = leaky(as.z + ad.z); a3 = leaky(as.w + ad.w);
    }
    float m0 = a0, m1 = a1, m2 = a2, m3 = a3;
    for (int o = 32; o > 0; o >>= 1) {
        m0 = fmaxf(m0, __shfl_xor(m0, o)); m1 = fmaxf(m1, __shfl_xor(m1, o));
        m2 = fmaxf(m2, __shfl_xor(m2, o)); m3 = fmaxf(m3, __shfl_xor(m3, o));
    }
    float w0 = lane < deg ? expf(a0 - m0) : 0.f;
    float w1 = lane < deg ? expf(a1 - m1) : 0.f;
    float w2 = lane < deg ? expf(a2 - m2) : 0.f;
    float w3 = lane < deg ? expf(a3 - m3) : 0.f;
    float t0 = w0, t1 = w1, t2 = w2, t3 = w3;
    for (int o = 32; o > 0; o >>= 1) {
        t0 += __shfl_xor(t0, o); t1 += __shfl_xor(t1, o);
        t2 += __shfl_xor(t2, o); t3 += __shfl_xor(t3, o);
    }
    w0 /= (t0 + EPS); w1 /= (t1 + EPS); w2 /= (t2 + EPS); w3 /= (t3 + EPS);
    if (lane < deg) {
        sw[0][wave][lane] = w0; sw[1][wave][lane] = w1;
        sw[2][wave][lane] = w2; sw[3][wave][lane] = w3;
        ss[wave][lane] = s;
    }
    int head = lane >> 4;
    float c0 = 0.f, c1 = 0.f, c2 = 0.f, c3 = 0.f;
    ushort4 hcur = *(const ushort4*)(h1b + (size_t)ss[wave][0] * 256 + lane * 4);
    float   wcur = sw[head][wave][0];
    for (int e = 1; e < deg; ++e) {
        ushort4 hnx = *(const ushort4*)(h1b + (size_t)ss[wave][e] * 256 + lane * 4);
        float   wnx = sw[head][wave][e];
        c0 = fmaf(bf2f(hcur.x), wcur, c0); c1 = fmaf(bf2f(hcur.y), wcur, c1);
        c2 = fmaf(bf2f(hcur.z), wcur, c2); c3 = fmaf(bf2f(hcur.w), wcur, c3);
        hcur = hnx; wcur = wnx;
    }
    c0 = fmaf(bf2f(hcur.x), wcur, c0); c1 = fmaf(bf2f(hcur.y), wcur, c1);
    c2 = fmaf(bf2f(hcur.z), wcur, c2); c3 = fmaf(bf2f(hcur.w), wcur, c3);

    float4 b = bias[lane];
    float o0 = elu(c0 + b.x), o1 = elu(c1 + b.y), o2 = elu(c2 + b.z), o3 = elu(c3 + b.w);
    *(ushort4*)&Ash[wave][lane * 4] = make_ushort4(f2bf(o0), f2bf(o1), f2bf(o2), f2bf(o3));
    float4 vs = v2s4[lane], vd = v2d4[lane];
    float ps = o0 * vs.x + o1 * vs.y + o2 * vs.z + o3 * vs.w;
    float pd = o0 * vd.x + o1 * vd.y + o2 * vd.z + o3 * vd.w;
    for (int o = 32; o > 0; o >>= 1) { ps += __shfl_xor(ps, o); pd += __shfl_xor(pd, o); }
    if (lane == 0) { a_src2[node] = ps; a_dst2[node] = pd; }

    __syncthreads();
    if (wave < 4) {
        int r = lane & 15, kg = lane >> 4;
        f32x4 acc = {0.f, 0.f, 0.f, 0.f};
        #pragma unroll
        for (int kk = 0; kk < 8; ++kk) {
            bf16x8 afr = *(const bf16x8*)&Ash[r][kg * 8 + kk * 32];
            bf16x8 bfr = *(const bf16x8*)(W2t + (size_t)(wave * 16 + r) * 256 + kg * 8 + kk * 32);
            acc = __builtin_amdgcn_mfma_f32_16x16x32_bf16(afr, bfr, acc, 0, 0, 0);
        }
        #pragma unroll
        for (int j = 0; j < 4; ++j)
            h2b[(size_t)(blockIdx.x * 16 + kg * 4 + j) * 64 + wave * 16 + r] = f2bf(acc[j]);
    }
}

// ---- FUSED layer 2: node gather (pipelined) + gate MFMA in-block ----
__global__ __launch_bounds__(1024)
void k_layer2(const unsigned short* __restrict__ ell, const unsigned* __restrict__ cnt_pad,
              const float* __restrict__ asrc, const float* __restrict__ adst,
              const unsigned short* __restrict__ h2b, const float* __restrict__ bias,
              const unsigned short* __restrict__ wg1h, const unsigned short* __restrict__ wg1l,
              const float* __restrict__ bg1, const float* __restrict__ Wg2,
              const float* __restrict__ bg2,
              float* __restrict__ out2, float* __restrict__ gate) {
    __shared__ float sw[16][MAX_DEG];
    __shared__ int   ss[16][MAX_DEG];
    __shared__ unsigned short Ah[16][72], Al[16][72];
    __shared__ float gp[4][16];
    int wave = threadIdx.x >> 6, lane = threadIdx.x & 63;
    int half = lane >> 5, li = lane & 31;
    int node = blockIdx.x * 16 + wave;
    int deg = min((int)cnt_pad[(size_t)node * CNT_STRIDE], MAX_DEG);

    float adv = adst[node];
    float a = -INFINITY;
    int s = 0;
    if (lane < deg) {
        s = ell[node * MAX_DEG + lane];
        a = leaky(asrc[s] + adv);
    }
    float m = a;
    for (int o = 32; o > 0; o >>= 1) m = fmaxf(m, __shfl_xor(m, o));
    float w = lane < deg ? expf(a - m) : 0.f;
    float t = w;
    for (int o = 32; o > 0; o >>= 1) t += __shfl_xor(t, o);
    w /= (t + EPS);
    if (lane < deg) { sw[wave][lane] = w; ss[wave][lane] = s; }

    float c0 = 0.f, c1 = 0.f;
    int row = half;
    unsigned ucur = 0; float wcur = 0.f;
    if (row < deg) {
        ucur = *(const unsigned*)(h2b + (size_t)ss[wave][row] * 64 + li * 2);
        wcur = sw[wave][row];
    }
    while (row < deg) {
        int nrow = row + 2;
        unsigned unx = 0; float wnx = 0.f;
        if (nrow < deg) {
            unx = *(const unsigned*)(h2b + (size_t)ss[wave][nrow] * 64 + li * 2);
            wnx = sw[wave][nrow];
        }
        c0 = fmaf(__uint_as_float(ucur << 16), wcur, c0);
        c1 = fmaf(__uint_as_float(ucur & 0xffff0000u), wcur, c1);
        ucur = unx; wcur = wnx; row = nrow;
    }
    c0 += __shfl_xor(c0, 32);
    c1 += __shfl_xor(c1, 32);
    if (half == 0) {
        float o0 = elu(c0 + bias[li * 2]);
        float o1 = elu(c1 + bias[li * 2 + 1]);
        *(float2*)(out2 + (size_t)node * 64 + li * 2) = make_float2(o0, o1);
        unsigned short h0 = f2bf(o0), h1 = f2bf(o1);
        *(unsigned*)&Ah[wave][li * 2] = ((unsigned)h1 << 16) | h0;
        unsigned short l0 = f2bf(o0 - bf2f(h0)), l1 = f2bf(o1 - bf2f(h1));
        *(unsigned*)&Al[wave][li * 2] = ((unsigned)l1 << 16) | l0;
    }

    __syncthreads();
    if (wave < 4) {
        int r = lane & 15, kg = lane >> 4;
        const bf16x8* Bh = (const bf16x8*)(wg1h + (size_t)(wave * 16 + r) * 64 + kg * 8);
        const bf16x8* Bl = (const bf16x8*)(wg1l + (size_t)(wave * 16 + r) * 64 + kg * 8);
        bf16x8 ah0 = *(const bf16x8*)&Ah[r][kg * 8];
        bf16x8 ah1 = *(const bf16x8*)&Ah[r][kg * 8 + 32];
        bf16x8 al0 = *(const bf16x8*)&Al[r][kg * 8];
        bf16x8 al1 = *(const bf16x8*)&Al[r][kg * 8 + 32];
        f32x4 acc = {0.f, 0.f, 0.f, 0.f};
        acc = __builtin_amdgcn_mfma_f32_16x16x32_bf16(ah0, Bh[0], acc, 0, 0, 0);
        acc = __builtin_amdgcn_mfma_f32_16x16x32_bf16(ah1, Bh[4], acc, 0, 0, 0);
        acc = __builtin_amdgcn_mfma_f32_16x16x32_bf16(ah0, Bl[0], acc, 0, 0, 0);
        acc = __builtin_amdgcn_mfma_f32_16x16x32_bf16(ah1, Bl[4], acc, 0, 0, 0);
        acc = __builtin_amdgcn_mfma_f32_16x16x32_bf16(al0, Bh[0], acc, 0, 0, 0);
        acc = __builtin_amdgcn_mfma_f32_16x16x32_bf16(al1, Bh[4], acc, 0, 0, 0);
        int col = wave * 16 + r;
        float wg2 = Wg2[col], bb = bg1[col];
        float part[4];
        #pragma unroll
        for (int j = 0; j < 4; ++j) part[j] = fmaxf(acc[j] + bb, 0.f) * wg2;
        #pragma unroll
        for (int o = 8; o > 0; o >>= 1) {
            #pragma unroll
            for (int j = 0; j < 4; ++j) part[j] += __shfl_xor(part[j], o);
        }
        if (r == 0) {
            #pragma unroll
            for (int j = 0; j < 4; ++j) gp[wave][kg * 4 + j] = part[j];
        }
    }
    __syncthreads();
    if (threadIdx.x < 16)
        gate[blockIdx.x * 16 + threadIdx.x] = gp[0][threadIdx.x] + gp[1][threadIdx.x]
                                            + gp[2][threadIdx.x] + gp[3][threadIdx.x] + bg2[0];
}

// ---- per-graph softmax + weighted aggregation (1024 threads) ----
__global__ __launch_bounds__(1024)
void k_final(const float* __restrict__ gate, const float* __restrict__ hfin,
             const int* __restrict__ batch, float* __restrict__ out) {
    __shared__ float red[16];
    __shared__ float redc[16][64];
    int g = blockIdx.x;
    int lo = lbound(batch, N_NODES, g);
    int hi = lbound(batch, N_NODES, g + 1);
    int tid = threadIdx.x, wave = tid >> 6, lane = tid & 63;

    float m = -INFINITY;
    for (int i = lo + tid; i < hi; i += 1024) m = fmaxf(m, gate[i]);
    for (int o = 32; o > 0; o >>= 1) m = fmaxf(m, __shfl_xor(m, o));
    if (lane == 0) red[wave] = m;
    __syncthreads();
    m = -INFINITY;
    #pragma unroll
    for (int i = 0; i < 16; ++i) m = fmaxf(m, red[i]);
    __syncthreads();

    float s = 0.f;
    for (int i = lo + tid; i < hi; i += 1024) s += expf(gate[i] - m);
    for (int o = 32; o > 0; o >>= 1) s += __shfl_xor(s, o);
    if (lane == 0) red[wave] = s;
    __syncthreads();
    s = 0.f;
    #pragma unroll
    for (int i = 0; i < 16; ++i) s += red[i];

    float acc = 0.f;
    for (int i = lo + wave; i < hi; i += 16)
        acc = fmaf(expf(gate[i] - m), hfin[(size_t)i * 64 + lane], acc);
    redc[wave][lane] = acc;
    __syncthreads();
    if (tid < 64) {
        float r = 0.f;
        #pragma unroll
        for (int i = 0; i < 16; ++i) r += redc[i][tid];
        out[g * 64 + tid] = r / (s + EPS);
    }
}

extern "C" void kernel_launch(void* const* d_in, const int* in_sizes, int n_in,
                              void* d_out, int out_size, void* d_ws, size_t ws_size,
                              hipStream_t stream) {
    const float* x    = (const float*)d_in[0];
    const int*   ei   = (const int*)d_in[1];
    const int*   batch= (const int*)d_in[2];
    const float* W1   = (const float*)d_in[3];
    const float* as1  = (const float*)d_in[4];
    const float* ad1  = (const float*)d_in[5];
    const float* b1   = (const float*)d_in[6];
    const float* W2   = (const float*)d_in[7];
    const float* as2  = (const float*)d_in[8];
    const float* ad2  = (const float*)d_in[9];
    const float* b2   = (const float*)d_in[10];
    const float* Wg1  = (const float*)d_in[11];
    const float* bg1  = (const float*)d_in[12];
    const float* Wg2  = (const float*)d_in[13];
    const float* bg2  = (const float*)d_in[14];
    float* out = (float*)d_out;

    char* W = (char*)d_ws;
    size_t off = 0;
    unsigned* cnt_pad = (unsigned*)(W + off); off += (size_t)N_NODES * CNT_STRIDE * 4;       // 6.4 MB
    unsigned short* ell  = (unsigned short*)(W + off); off += (size_t)N_NODES * MAX_DEG * 2; // 6.4 MB
    unsigned short* h1b  = (unsigned short*)(W + off); off += (size_t)N_NODES * 256 * 2;     // 25.6 MB
    float* a_src1 = (float*)(W + off); off += (size_t)N_NODES * HEADS * 4;
    float* a_dst1 = (float*)(W + off); off += (size_t)N_NODES * HEADS * 4;
    float* a_src2 = (float*)(W + off); off += (size_t)N_NODES * 4;
    float* a_dst2 = (float*)(W + off); off += (size_t)N_NODES * 4;
    float* out2   = (float*)(W + off); off += (size_t)N_NODES * HID * 4;                     // 12.8 MB
    float* gate   = (float*)(W + off); off += (size_t)N_NODES * 4;
    unsigned short* W1t = (unsigned short*)(W + off); off += (size_t)128 * 256 * 2;
    float* v1s = (float*)(W + off); off += 512 * 4;
    float* v1d = (float*)(W + off); off += 512 * 4;
    unsigned short* W2t = (unsigned short*)(W + off); off += (size_t)64 * 256 * 2;
    float* v2s = (float*)(W + off); off += 256 * 4;
    float* v2d = (float*)(W + off); off += 256 * 4;
    unsigned short* wg1h = (unsigned short*)(W + off); off += (size_t)64 * 64 * 2;
    unsigned short* wg1l = (unsigned short*)(W + off); off += (size_t)64 * 64 * 2;
    unsigned short* h2b = (unsigned short*)(W + off); off += (size_t)N_NODES * HID * 2;      // 6.4 MB
    (void)ws_size; (void)in_sizes; (void)n_in; (void)out_size;

    // 1: weights prep + cnt_pad zero
    k_wprep<<<96, 256, 0, stream>>>(W1, as1, ad1, W2, as2, ad2, Wg1,
                                    W1t, v1s, v1d, W2t, v2s, v2d, wg1h, wg1l,
                                    (uint4*)cnt_pad);
    // 2: gemm1 (+logit dots) | ELL build with line-padded counters
    k_prep2<<<G1_TILES + ELL_BLKS, 256, 0, stream>>>(x, W1t, v1s, v1d, h1b, a_src1, a_dst1,
                                                     ei, cnt_pad, ell);
    // 3: node1 gather + gemm2
    k_layer1<<<N_NODES / 16, 1024, 0, stream>>>(ell, cnt_pad, (const float4*)a_src1,
        (const float4*)a_dst1, h1b, (const float4*)b1,
        (const float4*)v2s, (const float4*)v2d, W2t, a_src2, a_dst2, h2b);
    // 4: node2 gather + gate MLP
    k_layer2<<<N_NODES / 16, 1024, 0, stream>>>(ell, cnt_pad, a_src2, a_dst2, h2b, b2,
                                                wg1h, wg1l, bg1, Wg2, bg2, out2, gate);
    // 5: per-graph softmax aggregation
    k_final<<<N_GRAPHS, 1024, 0, stream>>>(gate, out2, batch, out);
}

// Round 19
// 254.778 us; speedup vs baseline: 2.2760x; 1.0910x over previous
//
#include <hip/hip_runtime.h>
#include <math.h>

#define N_NODES 50000
#define N_EDGES 800000
#define E_TOT   850000
#define N_GRAPHS 64
#define EMB 128
#define HID 64
#define HEADS 4
#define NEG_SLOPE 0.2f
#define EPS 1e-16f
#define MAX_DEG 64
#define CNT_STRIDE 32
#define G1_TILES (N_NODES / 16)          // 3125
#define ELL_BLKS ((E_TOT + 255) / 256)   // 3322
#define INTERLEAVE (2 * G1_TILES)        // 6250: even->gemm1, odd->ELL

typedef short bf16x8 __attribute__((ext_vector_type(8)));
typedef float f32x4  __attribute__((ext_vector_type(4)));

__device__ __forceinline__ float leaky(float x) { return x >= 0.f ? x : NEG_SLOPE * x; }
__device__ __forceinline__ float elu(float x)   { return x > 0.f ? x : expf(x) - 1.f; }

__device__ __forceinline__ unsigned short f2bf(float f) {
    unsigned u = __float_as_uint(f);
    return (unsigned short)((u + 0x7FFFu + ((u >> 16) & 1u)) >> 16);
}
__device__ __forceinline__ float bf2f(unsigned short h) {
    return __uint_as_float((unsigned)h << 16);
}

__device__ __forceinline__ void edge_sd(const int* __restrict__ ei, int e, int& s, int& d) {
    if (e < N_EDGES) { s = ei[e]; d = ei[N_EDGES + e]; }
    else             { s = d = e - N_EDGES; }
}

__device__ __forceinline__ int lbound(const int* __restrict__ a, int n, int v) {
    int lo = 0, hi = n;
    while (lo < hi) { int mid = (lo + hi) >> 1; if (a[mid] < v) lo = mid + 1; else hi = mid; }
    return lo;
}

// ---- weight prep + cnt_pad zero (blocks 51-95) ----
__global__ void k_wprep(const float* __restrict__ W1, const float* __restrict__ as1, const float* __restrict__ ad1,
                        const float* __restrict__ W2, const float* __restrict__ as2, const float* __restrict__ ad2,
                        const float* __restrict__ Wg1,
                        unsigned short* __restrict__ W1t, float* __restrict__ v1s, float* __restrict__ v1d,
                        unsigned short* __restrict__ W2t, float* __restrict__ v2s, float* __restrict__ v2d,
                        unsigned short* __restrict__ wg1h, unsigned short* __restrict__ wg1l,
                        uint4* __restrict__ cnt_pad4) {
    int b = blockIdx.x, t = threadIdx.x;
    if (b < 32) {
        for (int i = b * 1024 + t; i < (b + 1) * 1024; i += 256) {
            int c = i >> 7, k = i & 127;
            W1t[i] = f2bf(W1[k * 256 + c]);
        }
    } else if (b < 48) {
        int bb = b - 32;
        for (int i = bb * 1024 + t; i < (bb + 1) * 1024; i += 256) {
            int c = i >> 8, k = i & 255;
            W2t[i] = f2bf(W2[k * 64 + c]);
        }
    } else if (b == 48) {
        for (int i = t; i < 512; i += 256) {
            int h = i >> 7, k = i & 127;
            float s = 0.f, d = 0.f;
            for (int c = 0; c < 64; ++c) {
                float wv = W1[k * 256 + h * 64 + c];
                s = fmaf(wv, as1[h * 64 + c], s);
                d = fmaf(wv, ad1[h * 64 + c], d);
            }
            v1s[i] = s; v1d[i] = d;
        }
    } else if (b == 49) {
        float s = 0.f, d = 0.f;
        for (int cc = 0; cc < 64; ++cc) {
            float wv = W2[t * 64 + cc];
            s = fmaf(wv, as2[cc], s);
            d = fmaf(wv, ad2[cc], d);
        }
        v2s[t] = s; v2d[t] = d;
    } else if (b == 50) {
        for (int i = t; i < 4096; i += 256) {
            int c = i >> 6, k = i & 63;
            float v = Wg1[k * 64 + c];
            unsigned short h = f2bf(v);
            wg1h[i] = h;
            wg1l[i] = f2bf(v - bf2f(h));
        }
    } else {
        const int total4 = N_NODES * CNT_STRIDE / 4;
        for (int i = (b - 51) * 256 + t; i < total4; i += 45 * 256)
            cnt_pad4[i] = make_uint4(0, 0, 0, 0);
    }
}

// ---- FUSED gemm1 | ELL, INTERLEAVED block mapping (even=gemm1, odd=ELL) ----
// so latency-bound ELL atomics hide under compute-bound gemm1 from t=0
__global__ __launch_bounds__(256)
void k_prep2(const float* __restrict__ x, const unsigned short* __restrict__ W1t,
             const float* __restrict__ v1s, const float* __restrict__ v1d,
             unsigned short* __restrict__ h1b, float* __restrict__ a_src1,
             float* __restrict__ a_dst1,
             const int* __restrict__ ei, unsigned* __restrict__ cnt_pad,
             unsigned short* __restrict__ ell) {
    int b = blockIdx.x;
    int tile, eblk;
    if (b < INTERLEAVE) { tile = b >> 1; eblk = b >> 1; }
    else                { tile = -1;     eblk = b - G1_TILES; }
    bool is_ell = (b >= INTERLEAVE) || (b & 1);
    if (is_ell) {
        int e = eblk * 256 + threadIdx.x;
        if (e < E_TOT) {
            int s, d; edge_sd(ei, e, s, d);
            unsigned slot = atomicAdd(&cnt_pad[(size_t)d * CNT_STRIDE], 1u);
            if (slot < MAX_DEG)
                ell[(size_t)d * MAX_DEG + slot] = (unsigned short)s;
        }
        return;
    }
    int w = threadIdx.x >> 6, l = threadIdx.x & 63;
    int r = l & 15, kg = l >> 4;
    const float* xr = x + (size_t)(tile * 16 + r) * 128 + kg * 8;
    bf16x8 af[4];
    float ps = 0.f, pd = 0.f;
    #pragma unroll
    for (int j = 0; j < 4; ++j) {
        float4 f0 = *(const float4*)(xr + j * 32);
        float4 f1 = *(const float4*)(xr + j * 32 + 4);
        const float* vs = v1s + w * 128 + j * 32 + kg * 8;
        const float* vd = v1d + w * 128 + j * 32 + kg * 8;
        float4 s0 = *(const float4*)vs, s1 = *(const float4*)(vs + 4);
        float4 d0 = *(const float4*)vd, d1 = *(const float4*)(vd + 4);
        ps += f0.x*s0.x + f0.y*s0.y + f0.z*s0.z + f0.w*s0.w
            + f1.x*s1.x + f1.y*s1.y + f1.z*s1.z + f1.w*s1.w;
        pd += f0.x*d0.x + f0.y*d0.y + f0.z*d0.z + f0.w*d0.w
            + f1.x*d1.x + f1.y*d1.y + f1.z*d1.z + f1.w*d1.w;
        bf16x8 t;
        t[0] = (short)f2bf(f0.x); t[1] = (short)f2bf(f0.y);
        t[2] = (short)f2bf(f0.z); t[3] = (short)f2bf(f0.w);
        t[4] = (short)f2bf(f1.x); t[5] = (short)f2bf(f1.y);
        t[6] = (short)f2bf(f1.z); t[7] = (short)f2bf(f1.w);
        af[j] = t;
    }
    ps += __shfl_xor(ps, 16); ps += __shfl_xor(ps, 32);
    pd += __shfl_xor(pd, 16); pd += __shfl_xor(pd, 32);
    if (l < 16) {
        a_src1[(size_t)(tile * 16 + r) * 4 + w] = ps;
        a_dst1[(size_t)(tile * 16 + r) * 4 + w] = pd;
    }
    for (int cc = 0; cc < 4; ++cc) {
        int c0 = cc * 64 + w * 16;
        const bf16x8* B = (const bf16x8*)(W1t + (size_t)(c0 + r) * 128 + kg * 8);
        f32x4 acc = {0.f, 0.f, 0.f, 0.f};
        acc = __builtin_amdgcn_mfma_f32_16x16x32_bf16(af[0], B[0],  acc, 0, 0, 0);
        acc = __builtin_amdgcn_mfma_f32_16x16x32_bf16(af[1], B[4],  acc, 0, 0, 0);
        acc = __builtin_amdgcn_mfma_f32_16x16x32_bf16(af[2], B[8],  acc, 0, 0, 0);
        acc = __builtin_amdgcn_mfma_f32_16x16x32_bf16(af[3], B[12], acc, 0, 0, 0);
        #pragma unroll
        for (int j = 0; j < 4; ++j)
            h1b[(size_t)(tile * 16 + kg * 4 + j) * 256 + c0 + r] = f2bf(acc[j]);
    }
}

// ---- FUSED layer 1: node gather (pipelined) + softmax + ELU, then gemm2 MFMA in-block ----
__global__ __launch_bounds__(1024)
void k_layer1(const unsigned short* __restrict__ ell, const unsigned* __restrict__ cnt_pad,
              const float4* __restrict__ asrc, const float4* __restrict__ adst,
              const unsigned short* __restrict__ h1b, const float4* __restrict__ bias,
              const float4* __restrict__ v2s4, const float4* __restrict__ v2d4,
              const unsigned short* __restrict__ W2t,
              float* __restrict__ a_src2, float* __restrict__ a_dst2,
              unsigned short* __restrict__ h2b) {
    __shared__ float sw[4][16][65];
    __shared__ int   ss[16][MAX_DEG];
    __shared__ unsigned short Ash[16][264];
    int wave = threadIdx.x >> 6, lane = threadIdx.x & 63;
    int node = blockIdx.x * 16 + wave;
    int deg = min((int)cnt_pad[(size_t)node * CNT_STRIDE], MAX_DEG);

    float4 ad = adst[node];
    float a0 = -INFINITY, a1 = -INFINITY, a2 = -INFINITY, a3 = -INFINITY;
    int s = 0;
    if (lane < deg) {
        s = ell[node * MAX_DEG + lane];
        float4 as = asrc[s];
        a0 = leaky(as.x + ad.x); a1 = leaky(as.y + ad.y);
        a2 = leaky(as.z + ad.z); a3 = leaky(as.w + ad.w);
    }
    float m0 = a0, m1 = a1, m2 = a2, m3 = a3;
    for (int o = 32; o > 0; o >>= 1) {
        m0 = fmaxf(m0, __shfl_xor(m0, o)); m1 = fmaxf(m1, __shfl_xor(m1, o));
        m2 = fmaxf(m2, __shfl_xor(m2, o)); m3 = fmaxf(m3, __shfl_xor(m3, o));
    }
    float w0 = lane < deg ? expf(a0 - m0) : 0.f;
    float w1 = lane < deg ? expf(a1 - m1) : 0.f;
    float w2 = lane < deg ? expf(a2 - m2) : 0.f;
    float w3 = lane < deg ? expf(a3 - m3) : 0.f;
    float t0 = w0, t1 = w1, t2 = w2, t3 = w3;
    for (int o = 32; o > 0; o >>= 1) {
        t0 += __shfl_xor(t0, o); t1 += __shfl_xor(t1, o);
        t2 += __shfl_xor(t2, o); t3 += __shfl_xor(t3, o);
    }
    w0 /= (t0 + EPS); w1 /= (t1 + EPS); w2 /= (t2 + EPS); w3 /= (t3 + EPS);
    if (lane < deg) {
        sw[0][wave][lane] = w0; sw[1][wave][lane] = w1;
        sw[2][wave][lane] = w2; sw[3][wave][lane] = w3;
        ss[wave][lane] = s;
    }
    int head = lane >> 4;
    float c0 = 0.f, c1 = 0.f, c2 = 0.f, c3 = 0.f;
    ushort4 hcur = *(const ushort4*)(h1b + (size_t)ss[wave][0] * 256 + lane * 4);
    float   wcur = sw[head][wave][0];
    for (int e = 1; e < deg; ++e) {
        ushort4 hnx = *(const ushort4*)(h1b + (size_t)ss[wave][e] * 256 + lane * 4);
        float   wnx = sw[head][wave][e];
        c0 = fmaf(bf2f(hcur.x), wcur, c0); c1 = fmaf(bf2f(hcur.y), wcur, c1);
        c2 = fmaf(bf2f(hcur.z), wcur, c2); c3 = fmaf(bf2f(hcur.w), wcur, c3);
        hcur = hnx; wcur = wnx;
    }
    c0 = fmaf(bf2f(hcur.x), wcur, c0); c1 = fmaf(bf2f(hcur.y), wcur, c1);
    c2 = fmaf(bf2f(hcur.z), wcur, c2); c3 = fmaf(bf2f(hcur.w), wcur, c3);

    float4 b = bias[lane];
    float o0 = elu(c0 + b.x), o1 = elu(c1 + b.y), o2 = elu(c2 + b.z), o3 = elu(c3 + b.w);
    *(ushort4*)&Ash[wave][lane * 4] = make_ushort4(f2bf(o0), f2bf(o1), f2bf(o2), f2bf(o3));
    float4 vs = v2s4[lane], vd = v2d4[lane];
    float ps = o0 * vs.x + o1 * vs.y + o2 * vs.z + o3 * vs.w;
    float pd = o0 * vd.x + o1 * vd.y + o2 * vd.z + o3 * vd.w;
    for (int o = 32; o > 0; o >>= 1) { ps += __shfl_xor(ps, o); pd += __shfl_xor(pd, o); }
    if (lane == 0) { a_src2[node] = ps; a_dst2[node] = pd; }

    __syncthreads();
    if (wave < 4) {
        int r = lane & 15, kg = lane >> 4;
        f32x4 acc = {0.f, 0.f, 0.f, 0.f};
        #pragma unroll
        for (int kk = 0; kk < 8; ++kk) {
            bf16x8 afr = *(const bf16x8*)&Ash[r][kg * 8 + kk * 32];
            bf16x8 bfr = *(const bf16x8*)(W2t + (size_t)(wave * 16 + r) * 256 + kg * 8 + kk * 32);
            acc = __builtin_amdgcn_mfma_f32_16x16x32_bf16(afr, bfr, acc, 0, 0, 0);
        }
        #pragma unroll
        for (int j = 0; j < 4; ++j)
            h2b[(size_t)(blockIdx.x * 16 + kg * 4 + j) * 64 + wave * 16 + r] = f2bf(acc[j]);
    }
}

// ---- FUSED layer 2: node gather (pipelined) + gate MFMA in-block ----
__global__ __launch_bounds__(1024)
void k_layer2(const unsigned short* __restrict__ ell, const unsigned* __restrict__ cnt_pad,
              const float* __restrict__ asrc, const float* __restrict__ adst,
              const unsigned short* __restrict__ h2b, const float* __restrict__ bias,
              const unsigned short* __restrict__ wg1h, const unsigned short* __restrict__ wg1l,
              const float* __restrict__ bg1, const float* __restrict__ Wg2,
              const float* __restrict__ bg2,
              float* __restrict__ out2, float* __restrict__ gate) {
    __shared__ float sw[16][MAX_DEG];
    __shared__ int   ss[16][MAX_DEG];
    __shared__ unsigned short Ah[16][72], Al[16][72];
    __shared__ float gp[4][16];
    int wave = threadIdx.x >> 6, lane = threadIdx.x & 63;
    int half = lane >> 5, li = lane & 31;
    int node = blockIdx.x * 16 + wave;
    int deg = min((int)cnt_pad[(size_t)node * CNT_STRIDE], MAX_DEG);

    float adv = adst[node];
    float a = -INFINITY;
    int s = 0;
    if (lane < deg) {
        s = ell[node * MAX_DEG + lane];
        a = leaky(asrc[s] + adv);
    }
    float m = a;
    for (int o = 32; o > 0; o >>= 1) m = fmaxf(m, __shfl_xor(m, o));
    float w = lane < deg ? expf(a - m) : 0.f;
    float t = w;
    for (int o = 32; o > 0; o >>= 1) t += __shfl_xor(t, o);
    w /= (t + EPS);
    if (lane < deg) { sw[wave][lane] = w; ss[wave][lane] = s; }

    float c0 = 0.f, c1 = 0.f;
    int row = half;
    unsigned ucur = 0; float wcur = 0.f;
    if (row < deg) {
        ucur = *(const unsigned*)(h2b + (size_t)ss[wave][row] * 64 + li * 2);
        wcur = sw[wave][row];
    }
    while (row < deg) {
        int nrow = row + 2;
        unsigned unx = 0; float wnx = 0.f;
        if (nrow < deg) {
            unx = *(const unsigned*)(h2b + (size_t)ss[wave][nrow] * 64 + li * 2);
            wnx = sw[wave][nrow];
        }
        c0 = fmaf(__uint_as_float(ucur << 16), wcur, c0);
        c1 = fmaf(__uint_as_float(ucur & 0xffff0000u), wcur, c1);
        ucur = unx; wcur = wnx; row = nrow;
    }
    c0 += __shfl_xor(c0, 32);
    c1 += __shfl_xor(c1, 32);
    if (half == 0) {
        float o0 = elu(c0 + bias[li * 2]);
        float o1 = elu(c1 + bias[li * 2 + 1]);
        *(float2*)(out2 + (size_t)node * 64 + li * 2) = make_float2(o0, o1);
        unsigned short h0 = f2bf(o0), h1 = f2bf(o1);
        *(unsigned*)&Ah[wave][li * 2] = ((unsigned)h1 << 16) | h0;
        unsigned short l0 = f2bf(o0 - bf2f(h0)), l1 = f2bf(o1 - bf2f(h1));
        *(unsigned*)&Al[wave][li * 2] = ((unsigned)l1 << 16) | l0;
    }

    __syncthreads();
    if (wave < 4) {
        int r = lane & 15, kg = lane >> 4;
        const bf16x8* Bh = (const bf16x8*)(wg1h + (size_t)(wave * 16 + r) * 64 + kg * 8);
        const bf16x8* Bl = (const bf16x8*)(wg1l + (size_t)(wave * 16 + r) * 64 + kg * 8);
        bf16x8 ah0 = *(const bf16x8*)&Ah[r][kg * 8];
        bf16x8 ah1 = *(const bf16x8*)&Ah[r][kg * 8 + 32];
        bf16x8 al0 = *(const bf16x8*)&Al[r][kg * 8];
        bf16x8 al1 = *(const bf16x8*)&Al[r][kg * 8 + 32];
        f32x4 acc = {0.f, 0.f, 0.f, 0.f};
        acc = __builtin_amdgcn_mfma_f32_16x16x32_bf16(ah0, Bh[0], acc, 0, 0, 0);
        acc = __builtin_amdgcn_mfma_f32_16x16x32_bf16(ah1, Bh[4], acc, 0, 0, 0);
        acc = __builtin_amdgcn_mfma_f32_16x16x32_bf16(ah0, Bl[0], acc, 0, 0, 0);
        acc = __builtin_amdgcn_mfma_f32_16x16x32_bf16(ah1, Bl[4], acc, 0, 0, 0);
        acc = __builtin_amdgcn_mfma_f32_16x16x32_bf16(al0, Bh[0], acc, 0, 0, 0);
        acc = __builtin_amdgcn_mfma_f32_16x16x32_bf16(al1, Bh[4], acc, 0, 0, 0);
        int col = wave * 16 + r;
        float wg2 = Wg2[col], bb = bg1[col];
        float part[4];
        #pragma unroll
        for (int j = 0; j < 4; ++j) part[j] = fmaxf(acc[j] + bb, 0.f) * wg2;
        #pragma unroll
        for (int o = 8; o > 0; o >>= 1) {
            #pragma unroll
            for (int j = 0; j < 4; ++j) part[j] += __shfl_xor(part[j], o);
        }
        if (r == 0) {
            #pragma unroll
            for (int j = 0; j < 4; ++j) gp[wave][kg * 4 + j] = part[j];
        }
    }
    __syncthreads();
    if (threadIdx.x < 16)
        gate[blockIdx.x * 16 + threadIdx.x] = gp[0][threadIdx.x] + gp[1][threadIdx.x]
                                            + gp[2][threadIdx.x] + gp[3][threadIdx.x] + bg2[0];
}

// ---- per-graph softmax + weighted aggregation (1024 threads) ----
__global__ __launch_bounds__(1024)
void k_final(const float* __restrict__ gate, const float* __restrict__ hfin,
             const int* __restrict__ batch, float* __restrict__ out) {
    __shared__ float red[16];
    __shared__ float redc[16][64];
    int g = blockIdx.x;
    int lo = lbound(batch, N_NODES, g);
    int hi = lbound(batch, N_NODES, g + 1);
    int tid = threadIdx.x, wave = tid >> 6, lane = tid & 63;

    float m = -INFINITY;
    for (int i = lo + tid; i < hi; i += 1024) m = fmaxf(m, gate[i]);
    for (int o = 32; o > 0; o >>= 1) m = fmaxf(m, __shfl_xor(m, o));
    if (lane == 0) red[wave] = m;
    __syncthreads();
    m = -INFINITY;
    #pragma unroll
    for (int i = 0; i < 16; ++i) m = fmaxf(m, red[i]);
    __syncthreads();

    float s = 0.f;
    for (int i = lo + tid; i < hi; i += 1024) s += expf(gate[i] - m);
    for (int o = 32; o > 0; o >>= 1) s += __shfl_xor(s, o);
    if (lane == 0) red[wave] = s;
    __syncthreads();
    s = 0.f;
    #pragma unroll
    for (int i = 0; i < 16; ++i) s += red[i];

    float acc = 0.f;
    for (int i = lo + wave; i < hi; i += 16)
        acc = fmaf(expf(gate[i] - m), hfin[(size_t)i * 64 + lane], acc);
    redc[wave][lane] = acc;
    __syncthreads();
    if (tid < 64) {
        float r = 0.f;
        #pragma unroll
        for (int i = 0; i < 16; ++i) r += redc[i][tid];
        out[g * 64 + tid] = r / (s + EPS);
    }
}

extern "C" void kernel_launch(void* const* d_in, const int* in_sizes, int n_in,
                              void* d_out, int out_size, void* d_ws, size_t ws_size,
                              hipStream_t stream) {
    const float* x    = (const float*)d_in[0];
    const int*   ei   = (const int*)d_in[1];
    const int*   batch= (const int*)d_in[2];
    const float* W1   = (const float*)d_in[3];
    const float* as1  = (const float*)d_in[4];
    const float* ad1  = (const float*)d_in[5];
    const float* b1   = (const float*)d_in[6];
    const float* W2   = (const float*)d_in[7];
    const float* as2  = (const float*)d_in[8];
    const float* ad2  = (const float*)d_in[9];
    const float* b2   = (const float*)d_in[10];
    const float* Wg1  = (const float*)d_in[11];
    const float* bg1  = (const float*)d_in[12];
    const float* Wg2  = (const float*)d_in[13];
    const float* bg2  = (const float*)d_in[14];
    float* out = (float*)d_out;

    char* W = (char*)d_ws;
    size_t off = 0;
    unsigned* cnt_pad = (unsigned*)(W + off); off += (size_t)N_NODES * CNT_STRIDE * 4;
    unsigned short* ell  = (unsigned short*)(W + off); off += (size_t)N_NODES * MAX_DEG * 2;
    unsigned short* h1b  = (unsigned short*)(W + off); off += (size_t)N_NODES * 256 * 2;
    float* a_src1 = (float*)(W + off); off += (size_t)N_NODES * HEADS * 4;
    float* a_dst1 = (float*)(W + off); off += (size_t)N_NODES * HEADS * 4;
    float* a_src2 = (float*)(W + off); off += (size_t)N_NODES * 4;
    float* a_dst2 = (float*)(W + off); off += (size_t)N_NODES * 4;
    float* out2   = (float*)(W + off); off += (size_t)N_NODES * HID * 4;
    float* gate   = (float*)(W + off); off += (size_t)N_NODES * 4;
    unsigned short* W1t = (unsigned short*)(W + off); off += (size_t)128 * 256 * 2;
    float* v1s = (float*)(W + off); off += 512 * 4;
    float* v1d = (float*)(W + off); off += 512 * 4;
    unsigned short* W2t = (unsigned short*)(W + off); off += (size_t)64 * 256 * 2;
    float* v2s = (float*)(W + off); off += 256 * 4;
    float* v2d = (float*)(W + off); off += 256 * 4;
    unsigned short* wg1h = (unsigned short*)(W + off); off += (size_t)64 * 64 * 2;
    unsigned short* wg1l = (unsigned short*)(W + off); off += (size_t)64 * 64 * 2;
    unsigned short* h2b = (unsigned short*)(W + off); off += (size_t)N_NODES * HID * 2;
    (void)ws_size; (void)in_sizes; (void)n_in; (void)out_size;

    // 1: weights prep + cnt_pad zero
    k_wprep<<<96, 256, 0, stream>>>(W1, as1, ad1, W2, as2, ad2, Wg1,
                                    W1t, v1s, v1d, W2t, v2s, v2d, wg1h, wg1l,
                                    (uint4*)cnt_pad);
    // 2: gemm1 | ELL, interleaved
    k_prep2<<<G1_TILES + ELL_BLKS, 256, 0, stream>>>(x, W1t, v1s, v1d, h1b, a_src1, a_dst1,
                                                     ei, cnt_pad, ell);
    // 3: node1 gather + gemm2
    k_layer1<<<N_NODES / 16, 1024, 0, stream>>>(ell, cnt_pad, (const float4*)a_src1,
        (const float4*)a_dst1, h1b, (const float4*)b1,
        (const float4*)v2s, (const float4*)v2d, W2t, a_src2, a_dst2, h2b);
    // 4: node2 gather + gate MLP
    k_layer2<<<N_NODES / 16, 1024, 0, stream>>>(ell, cnt_pad, a_src2, a_dst2, h2b, b2,
                                                wg1h, wg1l, bg1, Wg2, bg2, out2, gate);
    // 5: per-graph softmax aggregation
    k_final<<<N_GRAPHS, 1024, 0, stream>>>(gate, out2, batch, out);
}

// Round 20
// 239.068 us; speedup vs baseline: 2.4255x; 1.0657x over previous
//
#include <hip/hip_runtime.h>
#include <math.h>

#define N_NODES 50000
#define N_EDGES 800000
#define E_TOT   850000
#define N_GRAPHS 64
#define EMB 128
#define HID 64
#define HEADS 4
#define NEG_SLOPE 0.2f
#define EPS 1e-16f
#define MAX_DEG 64
#define CNT_STRIDE 32
#define G1_TILES (N_NODES / 16)              // 3125
#define ELL_EPT 4                            // edges per thread
#define ELL_BLKS ((E_TOT + 1023) / 1024)     // 831 blocks of 256 thr x 4 edges
#define INTERLEAVE (2 * ELL_BLKS)            // 1662: even->gemm1, odd->ELL

typedef short bf16x8 __attribute__((ext_vector_type(8)));
typedef float f32x4  __attribute__((ext_vector_type(4)));

__device__ __forceinline__ float leaky(float x) { return x >= 0.f ? x : NEG_SLOPE * x; }
__device__ __forceinline__ float elu(float x)   { return x > 0.f ? x : expf(x) - 1.f; }

__device__ __forceinline__ unsigned short f2bf(float f) {
    unsigned u = __float_as_uint(f);
    return (unsigned short)((u + 0x7FFFu + ((u >> 16) & 1u)) >> 16);
}
__device__ __forceinline__ float bf2f(unsigned short h) {
    return __uint_as_float((unsigned)h << 16);
}

__device__ __forceinline__ void edge_sd(const int* __restrict__ ei, int e, int& s, int& d) {
    if (e < N_EDGES) { s = ei[e]; d = ei[N_EDGES + e]; }
    else             { s = d = e - N_EDGES; }
}

__device__ __forceinline__ int lbound(const int* __restrict__ a, int n, int v) {
    int lo = 0, hi = n;
    while (lo < hi) { int mid = (lo + hi) >> 1; if (a[mid] < v) lo = mid + 1; else hi = mid; }
    return lo;
}

// ---- weight prep + cnt_pad zero (blocks 51-95) ----
__global__ void k_wprep(const float* __restrict__ W1, const float* __restrict__ as1, const float* __restrict__ ad1,
                        const float* __restrict__ W2, const float* __restrict__ as2, const float* __restrict__ ad2,
                        const float* __restrict__ Wg1,
                        unsigned short* __restrict__ W1t, float* __restrict__ v1s, float* __restrict__ v1d,
                        unsigned short* __restrict__ W2t, float* __restrict__ v2s, float* __restrict__ v2d,
                        unsigned short* __restrict__ wg1h, unsigned short* __restrict__ wg1l,
                        uint4* __restrict__ cnt_pad4) {
    int b = blockIdx.x, t = threadIdx.x;
    if (b < 32) {
        for (int i = b * 1024 + t; i < (b + 1) * 1024; i += 256) {
            int c = i >> 7, k = i & 127;
            W1t[i] = f2bf(W1[k * 256 + c]);
        }
    } else if (b < 48) {
        int bb = b - 32;
        for (int i = bb * 1024 + t; i < (bb + 1) * 1024; i += 256) {
            int c = i >> 8, k = i & 255;
            W2t[i] = f2bf(W2[k * 64 + c]);
        }
    } else if (b == 48) {
        for (int i = t; i < 512; i += 256) {
            int h = i >> 7, k = i & 127;
            float s = 0.f, d = 0.f;
            for (int c = 0; c < 64; ++c) {
                float wv = W1[k * 256 + h * 64 + c];
                s = fmaf(wv, as1[h * 64 + c], s);
                d = fmaf(wv, ad1[h * 64 + c], d);
            }
            v1s[i] = s; v1d[i] = d;
        }
    } else if (b == 49) {
        float s = 0.f, d = 0.f;
        for (int cc = 0; cc < 64; ++cc) {
            float wv = W2[t * 64 + cc];
            s = fmaf(wv, as2[cc], s);
            d = fmaf(wv, ad2[cc], d);
        }
        v2s[t] = s; v2d[t] = d;
    } else if (b == 50) {
        for (int i = t; i < 4096; i += 256) {
            int c = i >> 6, k = i & 63;
            float v = Wg1[k * 64 + c];
            unsigned short h = f2bf(v);
            wg1h[i] = h;
            wg1l[i] = f2bf(v - bf2f(h));
        }
    } else {
        const int total4 = N_NODES * CNT_STRIDE / 4;
        for (int i = (b - 51) * 256 + t; i < total4; i += 45 * 256)
            cnt_pad4[i] = make_uint4(0, 0, 0, 0);
    }
}

// ---- FUSED gemm1 | ELL (4 edges/thread, batched atomics), interleaved mapping ----
__global__ __launch_bounds__(256)
void k_prep2(const float* __restrict__ x, const unsigned short* __restrict__ W1t,
             const float* __restrict__ v1s, const float* __restrict__ v1d,
             unsigned short* __restrict__ h1b, float* __restrict__ a_src1,
             float* __restrict__ a_dst1,
             const int* __restrict__ ei, unsigned* __restrict__ cnt_pad,
             unsigned short* __restrict__ ell) {
    int b = blockIdx.x;
    int tile, eblk;
    bool is_ell;
    if (b < INTERLEAVE) { is_ell = (b & 1); tile = b >> 1; eblk = b >> 1; }
    else                { is_ell = false;   tile = b - ELL_BLKS; eblk = 0; }
    if (is_ell) {
        int e0 = eblk * 1024 + threadIdx.x;
        int sv[ELL_EPT], dv[ELL_EPT];
        unsigned slot[ELL_EPT];
        #pragma unroll
        for (int k = 0; k < ELL_EPT; ++k) {
            int e = e0 + k * 256;
            if (e < E_TOT) edge_sd(ei, e, sv[k], dv[k]);
            else { sv[k] = -1; dv[k] = 0; }
        }
        #pragma unroll
        for (int k = 0; k < ELL_EPT; ++k)
            slot[k] = (sv[k] >= 0) ? atomicAdd(&cnt_pad[(size_t)dv[k] * CNT_STRIDE], 1u) : 0xFFFFu;
        #pragma unroll
        for (int k = 0; k < ELL_EPT; ++k)
            if (sv[k] >= 0 && slot[k] < MAX_DEG)
                ell[(size_t)dv[k] * MAX_DEG + slot[k]] = (unsigned short)sv[k];
        return;
    }
    int w = threadIdx.x >> 6, l = threadIdx.x & 63;
    int r = l & 15, kg = l >> 4;
    const float* xr = x + (size_t)(tile * 16 + r) * 128 + kg * 8;
    bf16x8 af[4];
    float ps = 0.f, pd = 0.f;
    #pragma unroll
    for (int j = 0; j < 4; ++j) {
        float4 f0 = *(const float4*)(xr + j * 32);
        float4 f1 = *(const float4*)(xr + j * 32 + 4);
        const float* vs = v1s + w * 128 + j * 32 + kg * 8;
        const float* vd = v1d + w * 128 + j * 32 + kg * 8;
        float4 s0 = *(const float4*)vs, s1 = *(const float4*)(vs + 4);
        float4 d0 = *(const float4*)vd, d1 = *(const float4*)(vd + 4);
        ps += f0.x*s0.x + f0.y*s0.y + f0.z*s0.z + f0.w*s0.w
            + f1.x*s1.x + f1.y*s1.y + f1.z*s1.z + f1.w*s1.w;
        pd += f0.x*d0.x + f0.y*d0.y + f0.z*d0.z + f0.w*d0.w
            + f1.x*d1.x + f1.y*d1.y + f1.z*d1.z + f1.w*d1.w;
        bf16x8 t;
        t[0] = (short)f2bf(f0.x); t[1] = (short)f2bf(f0.y);
        t[2] = (short)f2bf(f0.z); t[3] = (short)f2bf(f0.w);
        t[4] = (short)f2bf(f1.x); t[5] = (short)f2bf(f1.y);
        t[6] = (short)f2bf(f1.z); t[7] = (short)f2bf(f1.w);
        af[j] = t;
    }
    ps += __shfl_xor(ps, 16); ps += __shfl_xor(ps, 32);
    pd += __shfl_xor(pd, 16); pd += __shfl_xor(pd, 32);
    if (l < 16) {
        a_src1[(size_t)(tile * 16 + r) * 4 + w] = ps;
        a_dst1[(size_t)(tile * 16 + r) * 4 + w] = pd;
    }
    for (int cc = 0; cc < 4; ++cc) {
        int c0 = cc * 64 + w * 16;
        const bf16x8* B = (const bf16x8*)(W1t + (size_t)(c0 + r) * 128 + kg * 8);
        f32x4 acc = {0.f, 0.f, 0.f, 0.f};
        acc = __builtin_amdgcn_mfma_f32_16x16x32_bf16(af[0], B[0],  acc, 0, 0, 0);
        acc = __builtin_amdgcn_mfma_f32_16x16x32_bf16(af[1], B[4],  acc, 0, 0, 0);
        acc = __builtin_amdgcn_mfma_f32_16x16x32_bf16(af[2], B[8],  acc, 0, 0, 0);
        acc = __builtin_amdgcn_mfma_f32_16x16x32_bf16(af[3], B[12], acc, 0, 0, 0);
        #pragma unroll
        for (int j = 0; j < 4; ++j)
            h1b[(size_t)(tile * 16 + kg * 4 + j) * 256 + c0 + r] = f2bf(acc[j]);
    }
}

// ---- FUSED layer 1: node gather (pipelined) + softmax + ELU, then gemm2 MFMA in-block ----
__global__ __launch_bounds__(1024)
void k_layer1(const unsigned short* __restrict__ ell, const unsigned* __restrict__ cnt_pad,
              const float4* __restrict__ asrc, const float4* __restrict__ adst,
              const unsigned short* __restrict__ h1b, const float4* __restrict__ bias,
              const float4* __restrict__ v2s4, const float4* __restrict__ v2d4,
              const unsigned short* __restrict__ W2t,
              float* __restrict__ a_src2, float* __restrict__ a_dst2,
              unsigned short* __restrict__ h2b) {
    __shared__ float sw[4][16][65];
    __shared__ int   ss[16][MAX_DEG];
    __shared__ unsigned short Ash[16][264];
    int wave = threadIdx.x >> 6, lane = threadIdx.x & 63;
    int node = blockIdx.x * 16 + wave;
    int deg = min((int)cnt_pad[(size_t)node * CNT_STRIDE], MAX_DEG);

    float4 ad = adst[node];
    float a0 = -INFINITY, a1 = -INFINITY, a2 = -INFINITY, a3 = -INFINITY;
    int s = 0;
    if (lane < deg) {
        s = ell[node * MAX_DEG + lane];
        float4 as = asrc[s];
        a0 = leaky(as.x + ad.x); a1 = leaky(as.y + ad.y);
        a2 = leaky(as.z + ad.z); a3 = leaky(as.w + ad.w);
    }
    float m0 = a0, m1 = a1, m2 = a2, m3 = a3;
    for (int o = 32; o > 0; o >>= 1) {
        m0 = fmaxf(m0, __shfl_xor(m0, o)); m1 = fmaxf(m1, __shfl_xor(m1, o));
        m2 = fmaxf(m2, __shfl_xor(m2, o)); m3 = fmaxf(m3, __shfl_xor(m3, o));
    }
    float w0 = lane < deg ? expf(a0 - m0) : 0.f;
    float w1 = lane < deg ? expf(a1 - m1) : 0.f;
    float w2 = lane < deg ? expf(a2 - m2) : 0.f;
    float w3 = lane < deg ? expf(a3 - m3) : 0.f;
    float t0 = w0, t1 = w1, t2 = w2, t3 = w3;
    for (int o = 32; o > 0; o >>= 1) {
        t0 += __shfl_xor(t0, o); t1 += __shfl_xor(t1, o);
        t2 += __shfl_xor(t2, o); t3 += __shfl_xor(t3, o);
    }
    w0 /= (t0 + EPS); w1 /= (t1 + EPS); w2 /= (t2 + EPS); w3 /= (t3 + EPS);
    if (lane < deg) {
        sw[0][wave][lane] = w0; sw[1][wave][lane] = w1;
        sw[2][wave][lane] = w2; sw[3][wave][lane] = w3;
        ss[wave][lane] = s;
    }
    int head = lane >> 4;
    float c0 = 0.f, c1 = 0.f, c2 = 0.f, c3 = 0.f;
    ushort4 hcur = *(const ushort4*)(h1b + (size_t)ss[wave][0] * 256 + lane * 4);
    float   wcur = sw[head][wave][0];
    for (int e = 1; e < deg; ++e) {
        ushort4 hnx = *(const ushort4*)(h1b + (size_t)ss[wave][e] * 256 + lane * 4);
        float   wnx = sw[head][wave][e];
        c0 = fmaf(bf2f(hcur.x), wcur, c0); c1 = fmaf(bf2f(hcur.y), wcur, c1);
        c2 = fmaf(bf2f(hcur.z), wcur, c2); c3 = fmaf(bf2f(hcur.w), wcur, c3);
        hcur = hnx; wcur = wnx;
    }
    c0 = fmaf(bf2f(hcur.x), wcur, c0); c1 = fmaf(bf2f(hcur.y), wcur, c1);
    c2 = fmaf(bf2f(hcur.z), wcur, c2); c3 = fmaf(bf2f(hcur.w), wcur, c3);

    float4 b = bias[lane];
    float o0 = elu(c0 + b.x), o1 = elu(c1 + b.y), o2 = elu(c2 + b.z), o3 = elu(c3 + b.w);
    *(ushort4*)&Ash[wave][lane * 4] = make_ushort4(f2bf(o0), f2bf(o1), f2bf(o2), f2bf(o3));
    float4 vs = v2s4[lane], vd = v2d4[lane];
    float ps = o0 * vs.x + o1 * vs.y + o2 * vs.z + o3 * vs.w;
    float pd = o0 * vd.x + o1 * vd.y + o2 * vd.z + o3 * vd.w;
    for (int o = 32; o > 0; o >>= 1) { ps += __shfl_xor(ps, o); pd += __shfl_xor(pd, o); }
    if (lane == 0) { a_src2[node] = ps; a_dst2[node] = pd; }

    __syncthreads();
    if (wave < 4) {
        int r = lane & 15, kg = lane >> 4;
        f32x4 acc = {0.f, 0.f, 0.f, 0.f};
        #pragma unroll
        for (int kk = 0; kk < 8; ++kk) {
            bf16x8 afr = *(const bf16x8*)&Ash[r][kg * 8 + kk * 32];
            bf16x8 bfr = *(const bf16x8*)(W2t + (size_t)(wave * 16 + r) * 256 + kg * 8 + kk * 32);
            acc = __builtin_amdgcn_mfma_f32_16x16x32_bf16(afr, bfr, acc, 0, 0, 0);
        }
        #pragma unroll
        for (int j = 0; j < 4; ++j)
            h2b[(size_t)(blockIdx.x * 16 + kg * 4 + j) * 64 + wave * 16 + r] = f2bf(acc[j]);
    }
}

// ---- FUSED layer 2: node gather (pipelined) + gate MFMA in-block ----
__global__ __launch_bounds__(1024)
void k_layer2(const unsigned short* __restrict__ ell, const unsigned* __restrict__ cnt_pad,
              const float* __restrict__ asrc, const float* __restrict__ adst,
              const unsigned short* __restrict__ h2b, const float* __restrict__ bias,
              const unsigned short* __restrict__ wg1h, const unsigned short* __restrict__ wg1l,
              const float* __restrict__ bg1, const float* __restrict__ Wg2,
              const float* __restrict__ bg2,
              float* __restrict__ out2, float* __restrict__ gate) {
    __shared__ float sw[16][MAX_DEG];
    __shared__ int   ss[16][MAX_DEG];
    __shared__ unsigned short Ah[16][72], Al[16][72];
    __shared__ float gp[4][16];
    int wave = threadIdx.x >> 6, lane = threadIdx.x & 63;
    int half = lane >> 5, li = lane & 31;
    int node = blockIdx.x * 16 + wave;
    int deg = min((int)cnt_pad[(size_t)node * CNT_STRIDE], MAX_DEG);

    float adv = adst[node];
    float a = -INFINITY;
    int s = 0;
    if (lane < deg) {
        s = ell[node * MAX_DEG + lane];
        a = leaky(asrc[s] + adv);
    }
    float m = a;
    for (int o = 32; o > 0; o >>= 1) m = fmaxf(m, __shfl_xor(m, o));
    float w = lane < deg ? expf(a - m) : 0.f;
    float t = w;
    for (int o = 32; o > 0; o >>= 1) t += __shfl_xor(t, o);
    w /= (t + EPS);
    if (lane < deg) { sw[wave][lane] = w; ss[wave][lane] = s; }

    float c0 = 0.f, c1 = 0.f;
    int row = half;
    unsigned ucur = 0; float wcur = 0.f;
    if (row < deg) {
        ucur = *(const unsigned*)(h2b + (size_t)ss[wave][row] * 64 + li * 2);
        wcur = sw[wave][row];
    }
    while (row < deg) {
        int nrow = row + 2;
        unsigned unx = 0; float wnx = 0.f;
        if (nrow < deg) {
            unx = *(const unsigned*)(h2b + (size_t)ss[wave][nrow] * 64 + li * 2);
            wnx = sw[wave][nrow];
        }
        c0 = fmaf(__uint_as_float(ucur << 16), wcur, c0);
        c1 = fmaf(__uint_as_float(ucur & 0xffff0000u), wcur, c1);
        ucur = unx; wcur = wnx; row = nrow;
    }
    c0 += __shfl_xor(c0, 32);
    c1 += __shfl_xor(c1, 32);
    if (half == 0) {
        float o0 = elu(c0 + bias[li * 2]);
        float o1 = elu(c1 + bias[li * 2 + 1]);
        *(float2*)(out2 + (size_t)node * 64 + li * 2) = make_float2(o0, o1);
        unsigned short h0 = f2bf(o0), h1 = f2bf(o1);
        *(unsigned*)&Ah[wave][li * 2] = ((unsigned)h1 << 16) | h0;
        unsigned short l0 = f2bf(o0 - bf2f(h0)), l1 = f2bf(o1 - bf2f(h1));
        *(unsigned*)&Al[wave][li * 2] = ((unsigned)l1 << 16) | l0;
    }

    __syncthreads();
    if (wave < 4) {
        int r = lane & 15, kg = lane >> 4;
        const bf16x8* Bh = (const bf16x8*)(wg1h + (size_t)(wave * 16 + r) * 64 + kg * 8);
        const bf16x8* Bl = (const bf16x8*)(wg1l + (size_t)(wave * 16 + r) * 64 + kg * 8);
        bf16x8 ah0 = *(const bf16x8*)&Ah[r][kg * 8];
        bf16x8 ah1 = *(const bf16x8*)&Ah[r][kg * 8 + 32];
        bf16x8 al0 = *(const bf16x8*)&Al[r][kg * 8];
        bf16x8 al1 = *(const bf16x8*)&Al[r][kg * 8 + 32];
        f32x4 acc = {0.f, 0.f, 0.f, 0.f};
        acc = __builtin_amdgcn_mfma_f32_16x16x32_bf16(ah0, Bh[0], acc, 0, 0, 0);
        acc = __builtin_amdgcn_mfma_f32_16x16x32_bf16(ah1, Bh[4], acc, 0, 0, 0);
        acc = __builtin_amdgcn_mfma_f32_16x16x32_bf16(ah0, Bl[0], acc, 0, 0, 0);
        acc = __builtin_amdgcn_mfma_f32_16x16x32_bf16(ah1, Bl[4], acc, 0, 0, 0);
        acc = __builtin_amdgcn_mfma_f32_16x16x32_bf16(al0, Bh[0], acc, 0, 0, 0);
        acc = __builtin_amdgcn_mfma_f32_16x16x32_bf16(al1, Bh[4], acc, 0, 0, 0);
        int col = wave * 16 + r;
        float wg2 = Wg2[col], bb = bg1[col];
        float part[4];
        #pragma unroll
        for (int j = 0; j < 4; ++j) part[j] = fmaxf(acc[j] + bb, 0.f) * wg2;
        #pragma unroll
        for (int o = 8; o > 0; o >>= 1) {
            #pragma unroll
            for (int j = 0; j < 4; ++j) part[j] += __shfl_xor(part[j], o);
        }
        if (r == 0) {
            #pragma unroll
            for (int j = 0; j < 4; ++j) gp[wave][kg * 4 + j] = part[j];
        }
    }
    __syncthreads();
    if (threadIdx.x < 16)
        gate[blockIdx.x * 16 + threadIdx.x] = gp[0][threadIdx.x] + gp[1][threadIdx.x]
                                            + gp[2][threadIdx.x] + gp[3][threadIdx.x] + bg2[0];
}

// ---- per-graph softmax + weighted aggregation (1024 threads) ----
__global__ __launch_bounds__(1024)
void k_final(const float* __restrict__ gate, const float* __restrict__ hfin,
             const int* __restrict__ batch, float* __restrict__ out) {
    __shared__ float red[16];
    __shared__ float redc[16][64];
    int g = blockIdx.x;
    int lo = lbound(batch, N_NODES, g);
    int hi = lbound(batch, N_NODES, g + 1);
    int tid = threadIdx.x, wave = tid >> 6, lane = tid & 63;

    float m = -INFINITY;
    for (int i = lo + tid; i < hi; i += 1024) m = fmaxf(m, gate[i]);
    for (int o = 32; o > 0; o >>= 1) m = fmaxf(m, __shfl_xor(m, o));
    if (lane == 0) red[wave] = m;
    __syncthreads();
    m = -INFINITY;
    #pragma unroll
    for (int i = 0; i < 16; ++i) m = fmaxf(m, red[i]);
    __syncthreads();

    float s = 0.f;
    for (int i = lo + tid; i < hi; i += 1024) s += expf(gate[i] - m);
    for (int o = 32; o > 0; o >>= 1) s += __shfl_xor(s, o);
    if (lane == 0) red[wave] = s;
    __syncthreads();
    s = 0.f;
    #pragma unroll
    for (int i = 0; i < 16; ++i) s += red[i];

    float acc = 0.f;
    for (int i = lo + wave; i < hi; i += 16)
        acc = fmaf(expf(gate[i] - m), hfin[(size_t)i * 64 + lane], acc);
    redc[wave][lane] = acc;
    __syncthreads();
    if (tid < 64) {
        float r = 0.f;
        #pragma unroll
        for (int i = 0; i < 16; ++i) r += redc[i][tid];
        out[g * 64 + tid] = r / (s + EPS);
    }
}

extern "C" void kernel_launch(void* const* d_in, const int* in_sizes, int n_in,
                              void* d_out, int out_size, void* d_ws, size_t ws_size,
                              hipStream_t stream) {
    const float* x    = (const float*)d_in[0];
    const int*   ei   = (const int*)d_in[1];
    const int*   batch= (const int*)d_in[2];
    const float* W1   = (const float*)d_in[3];
    const float* as1  = (const float*)d_in[4];
    const float* ad1  = (const float*)d_in[5];
    const float* b1   = (const float*)d_in[6];
    const float* W2   = (const float*)d_in[7];
    const float* as2  = (const float*)d_in[8];
    const float* ad2  = (const float*)d_in[9];
    const float* b2   = (const float*)d_in[10];
    const float* Wg1  = (const float*)d_in[11];
    const float* bg1  = (const float*)d_in[12];
    const float* Wg2  = (const float*)d_in[13];
    const float* bg2  = (const float*)d_in[14];
    float* out = (float*)d_out;

    char* W = (char*)d_ws;
    size_t off = 0;
    unsigned* cnt_pad = (unsigned*)(W + off); off += (size_t)N_NODES * CNT_STRIDE * 4;
    unsigned short* ell  = (unsigned short*)(W + off); off += (size_t)N_NODES * MAX_DEG * 2;
    unsigned short* h1b  = (unsigned short*)(W + off); off += (size_t)N_NODES * 256 * 2;
    float* a_src1 = (float*)(W + off); off += (size_t)N_NODES * HEADS * 4;
    float* a_dst1 = (float*)(W + off); off += (size_t)N_NODES * HEADS * 4;
    float* a_src2 = (float*)(W + off); off += (size_t)N_NODES * 4;
    float* a_dst2 = (float*)(W + off); off += (size_t)N_NODES * 4;
    float* out2   = (float*)(W + off); off += (size_t)N_NODES * HID * 4;
    float* gate   = (float*)(W + off); off += (size_t)N_NODES * 4;
    unsigned short* W1t = (unsigned short*)(W + off); off += (size_t)128 * 256 * 2;
    float* v1s = (float*)(W + off); off += 512 * 4;
    float* v1d = (float*)(W + off); off += 512 * 4;
    unsigned short* W2t = (unsigned short*)(W + off); off += (size_t)64 * 256 * 2;
    float* v2s = (float*)(W + off); off += 256 * 4;
    float* v2d = (float*)(W + off); off += 256 * 4;
    unsigned short* wg1h = (unsigned short*)(W + off); off += (size_t)64 * 64 * 2;
    unsigned short* wg1l = (unsigned short*)(W + off); off += (size_t)64 * 64 * 2;
    unsigned short* h2b = (unsigned short*)(W + off); off += (size_t)N_NODES * HID * 2;
    (void)ws_size; (void)in_sizes; (void)n_in; (void)out_size;

    // 1: weights prep + cnt_pad zero
    k_wprep<<<96, 256, 0, stream>>>(W1, as1, ad1, W2, as2, ad2, Wg1,
                                    W1t, v1s, v1d, W2t, v2s, v2d, wg1h, wg1l,
                                    (uint4*)cnt_pad);
    // 2: gemm1 | ELL (4 edges/thread), interleaved
    k_prep2<<<G1_TILES + ELL_BLKS, 256, 0, stream>>>(x, W1t, v1s, v1d, h1b, a_src1, a_dst1,
                                                     ei, cnt_pad, ell);
    // 3: node1 gather + gemm2
    k_layer1<<<N_NODES / 16, 1024, 0, stream>>>(ell, cnt_pad, (const float4*)a_src1,
        (const float4*)a_dst1, h1b, (const float4*)b1,
        (const float4*)v2s, (const float4*)v2d, W2t, a_src2, a_dst2, h2b);
    // 4: node2 gather + gate MLP
    k_layer2<<<N_NODES / 16, 1024, 0, stream>>>(ell, cnt_pad, a_src2, a_dst2, h2b, b2,
                                                wg1h, wg1l, bg1, Wg2, bg2, out2, gate);
    // 5: per-graph softmax aggregation
    k_final<<<N_GRAPHS, 1024, 0, stream>>>(gate, out2, batch, out);
}